// Round 1
// baseline (523.469 us; speedup 1.0000x reference)
//
#include <hip/hip_runtime.h>

// Problem constants: B=4, N=1024, D=256, H=8
// qkv GEMM: [4096, 256] @ [256, 6144]
// Workspace layout (floats):
//   qkv2   : [3][B][H][N][D]  = 25165824   (seg 0=q, 1=k, 2=v; transposed layout)
//   pm     : [B][H][N][4]     = 131072     (partial softmax max, 4 n-chunks)
//   pl     : [B][H][N][4]     = 131072     (partial softmax sum)
//   sd     : [B][H][N]        = 32768      (raw diagonal score)
//   diag   : [B*N][H]         = 32768      (final diag attention weight)
//   partial: [8][4096][256]   = 8388608    (split-K over h for output GEMM; optional)

#define SEGSZ 8388608  // B*H*N*D = 4*8*1024*256

// ---------------------------------------------------------------------------
// Kernel A: qkv = x @ Wqkv + bqkv, scattered into [seg][b][h][n][d] layout.
// Tile 64 rows x 128 cols, 256 threads, 4x8 micro-tile, k-chunk 16.
// grid (48, 64)
// ---------------------------------------------------------------------------
__global__ __launch_bounds__(256) void qkv_gemm(
    const float* __restrict__ X, const float* __restrict__ W,
    const float* __restrict__ bias, float* __restrict__ qkv2) {
  __shared__ alignas(16) float Xs[16][68];   // [k][row], pad 68 for conflict-free transpose
  __shared__ alignas(16) float Ws[16][128];  // [k][col]
  const int tid = threadIdx.x;
  const int ty = tid >> 4, tx = tid & 15;
  const int r0 = blockIdx.y * 64;
  const int c0 = blockIdx.x * 128;

  float acc[4][8] = {};

  for (int k0 = 0; k0 < 256; k0 += 16) {
    {  // X tile: 64 rows x 16 k, transposed store
      const int row = tid >> 2;
      const int k4 = (tid & 3) << 2;
      const float4 v = *(const float4*)&X[(size_t)(r0 + row) * 256 + k0 + k4];
      Xs[k4 + 0][row] = v.x; Xs[k4 + 1][row] = v.y;
      Xs[k4 + 2][row] = v.z; Xs[k4 + 3][row] = v.w;
    }
    {  // W tile: 16 k x 128 cols, direct
      int idx = tid;
      int kk = idx >> 5, c4 = (idx & 31) << 2;
      *(float4*)&Ws[kk][c4] = *(const float4*)&W[(size_t)(k0 + kk) * 6144 + c0 + c4];
      idx = tid + 256;
      kk = idx >> 5; c4 = (idx & 31) << 2;
      *(float4*)&Ws[kk][c4] = *(const float4*)&W[(size_t)(k0 + kk) * 6144 + c0 + c4];
    }
    __syncthreads();
#pragma unroll
    for (int kk = 0; kk < 16; ++kk) {
      float a[4], bb[8];
      {
        const float4 t0_ = *(const float4*)&Xs[kk][ty * 4];
        a[0] = t0_.x; a[1] = t0_.y; a[2] = t0_.z; a[3] = t0_.w;
        const float4 b0_ = *(const float4*)&Ws[kk][tx * 4];
        const float4 b1_ = *(const float4*)&Ws[kk][64 + tx * 4];
        bb[0] = b0_.x; bb[1] = b0_.y; bb[2] = b0_.z; bb[3] = b0_.w;
        bb[4] = b1_.x; bb[5] = b1_.y; bb[6] = b1_.z; bb[7] = b1_.w;
      }
#pragma unroll
      for (int i = 0; i < 4; ++i)
#pragma unroll
        for (int j = 0; j < 8; ++j) acc[i][j] += a[i] * bb[j];
    }
    __syncthreads();
  }

  // Epilogue: scatter into [seg][b][h][n][d]
#pragma unroll
  for (int i = 0; i < 4; ++i) {
    const int r = r0 + ty * 4 + i;
#pragma unroll
    for (int j = 0; j < 8; ++j) {
      const int c = c0 + ((j < 4) ? (tx * 4 + j) : (64 + tx * 4 + (j - 4)));
      const float val = acc[i][j] + bias[c];
      const int g = r * 3 + (c >> 11);   // token-row in (3*B*N) space
      const int dh = c & 2047;
      const int d = dh >> 3, h = dh & 7;
      const int seg = g >> 12;
      const int tok = g & 4095;
      const size_t dst =
          ((((size_t)(seg * 4 + (tok >> 10)) * 8 + h) * 1024 + (tok & 1023)) << 8) + d;
      qkv2[dst] = val;
    }
  }
}

// ---------------------------------------------------------------------------
// Kernel B: score column reductions.  s[n,t] = scale * sum_d q[n,d]*k[t,d]
// per (b,h).  Softmax is over n (axis 1); we need per-(b,h,t): max_n, sum_n exp,
// and the diagonal s[t,t].  Split n into 4 chunks of 256 for occupancy.
// grid (32 = tt*4+chunk, 8 = h, 4 = b), 256 threads, 128(t) x 128(n) S-tiles,
// 8x8 micro-tile, d-chunk 16.
// ---------------------------------------------------------------------------
__global__ __launch_bounds__(256) void scores_kernel(
    const float* __restrict__ qkv2, float* __restrict__ pm,
    float* __restrict__ pl, float* __restrict__ sd_ws) {
  __shared__ alignas(16) float Qs[16][132];  // [d][n], pad 132
  __shared__ alignas(16) float Ks[16][132];  // [d][t]
  __shared__ float sdL[128];
  const int tid = threadIdx.x;
  const int ty = tid >> 4, tx = tid & 15;
  const int tt = blockIdx.x >> 2, chunk = blockIdx.x & 3;
  const int h = blockIdx.y, b = blockIdx.z;
  const int t0 = tt * 128;
  const float scale = 0.0625f;  // 256^-0.5
  const float* Qbase = qkv2 + (size_t)(b * 8 + h) * (1024 * 256);            // seg 0
  const float* Kbase = qkv2 + (size_t)((4 + b) * 8 + h) * (1024 * 256);      // seg 1

  float m_[8], l_[8];
#pragma unroll
  for (int j = 0; j < 8; ++j) { m_[j] = -1e30f; l_[j] = 0.f; }
  const bool hasDiag = (chunk == (tt >> 1));

  for (int sub = 0; sub < 2; ++sub) {
    const int n0 = chunk * 256 + sub * 128;
    float acc[8][8] = {};
    for (int d0 = 0; d0 < 256; d0 += 16) {
#pragma unroll
      for (int i2 = 0; i2 < 2; ++i2) {  // stage 128 rows x 16 d, transposed
        const int row = i2 * 64 + (tid >> 2);
        const int d4 = (tid & 3) << 2;
        const float4 qv = *(const float4*)&Qbase[((size_t)(n0 + row) << 8) + d0 + d4];
        const float4 kv = *(const float4*)&Kbase[((size_t)(t0 + row) << 8) + d0 + d4];
        Qs[d4 + 0][row] = qv.x; Qs[d4 + 1][row] = qv.y;
        Qs[d4 + 2][row] = qv.z; Qs[d4 + 3][row] = qv.w;
        Ks[d4 + 0][row] = kv.x; Ks[d4 + 1][row] = kv.y;
        Ks[d4 + 2][row] = kv.z; Ks[d4 + 3][row] = kv.w;
      }
      __syncthreads();
#pragma unroll
      for (int kk = 0; kk < 16; ++kk) {
        float a[8], bb[8];
        {
          const float4 a0_ = *(const float4*)&Qs[kk][ty * 4];
          const float4 a1_ = *(const float4*)&Qs[kk][64 + ty * 4];
          a[0] = a0_.x; a[1] = a0_.y; a[2] = a0_.z; a[3] = a0_.w;
          a[4] = a1_.x; a[5] = a1_.y; a[6] = a1_.z; a[7] = a1_.w;
          const float4 b0_ = *(const float4*)&Ks[kk][tx * 4];
          const float4 b1_ = *(const float4*)&Ks[kk][64 + tx * 4];
          bb[0] = b0_.x; bb[1] = b0_.y; bb[2] = b0_.z; bb[3] = b0_.w;
          bb[4] = b1_.x; bb[5] = b1_.y; bb[6] = b1_.z; bb[7] = b1_.w;
        }
#pragma unroll
        for (int i = 0; i < 8; ++i)
#pragma unroll
          for (int j = 0; j < 8; ++j) acc[i][j] += a[i] * bb[j];
      }
      __syncthreads();
    }
    // online softmax update over this subtile's 8 rows per column
#pragma unroll
    for (int j = 0; j < 8; ++j) {
      float mloc = acc[0][j] * scale;
#pragma unroll
      for (int i = 1; i < 8; ++i) mloc = fmaxf(mloc, acc[i][j] * scale);
      const float mnew = fmaxf(m_[j], mloc);
      float sum = 0.f;
#pragma unroll
      for (int i = 0; i < 8; ++i) sum += __expf(acc[i][j] * scale - mnew);
      l_[j] = l_[j] * __expf(m_[j] - mnew) + sum;
      m_[j] = mnew;
    }
    // diagonal capture (n0 global == t0 global happens in exactly one subtile)
    if (n0 == t0 && ty == tx) {
#pragma unroll
      for (int j = 0; j < 4; ++j) {
        sdL[tx * 4 + j] = acc[j][j] * scale;
        sdL[64 + tx * 4 + j] = acc[4 + j][4 + j] * scale;
      }
    }
  }

  // block-level column reduction: 16 (ty) partials per column; reuse Qs/Ks
#pragma unroll
  for (int j = 0; j < 8; ++j) {
    const int col = (j < 4) ? (tx * 4 + j) : (64 + tx * 4 + (j - 4));
    Qs[ty][col] = m_[j];
    Ks[ty][col] = l_[j];
  }
  __syncthreads();
  if (tid < 128) {
    const int col = tid;
    float m = -1e30f;
#pragma unroll
    for (int i = 0; i < 16; ++i) m = fmaxf(m, Qs[i][col]);
    float l = 0.f;
#pragma unroll
    for (int i = 0; i < 16; ++i) l += Ks[i][col] * __expf(Qs[i][col] - m);
    const int t = t0 + col;
    const size_t idx = (((size_t)(b * 8 + h) * 1024 + t) << 2) + chunk;
    pm[idx] = m;
    pl[idx] = l;
    if (hasDiag) sd_ws[(size_t)(b * 8 + h) * 1024 + t] = sdL[col];
  }
}

// ---------------------------------------------------------------------------
// Merge partial softmax stats -> diag[b*N + t][h]
// grid (128), 256 threads; 32768 = B*H*N entries
// ---------------------------------------------------------------------------
__global__ void merge_diag(const float* __restrict__ pm, const float* __restrict__ pl,
                           const float* __restrict__ sd, float* __restrict__ diag) {
  const int i = blockIdx.x * 256 + threadIdx.x;  // (b*8+h)*1024 + t
  const float m0 = pm[i * 4 + 0], m1 = pm[i * 4 + 1];
  const float m2 = pm[i * 4 + 2], m3 = pm[i * 4 + 3];
  const float m = fmaxf(fmaxf(m0, m1), fmaxf(m2, m3));
  const float l = pl[i * 4 + 0] * __expf(m0 - m) + pl[i * 4 + 1] * __expf(m1 - m) +
                  pl[i * 4 + 2] * __expf(m2 - m) + pl[i * 4 + 3] * __expf(m3 - m);
  const float dg = __expf(sd[i] - m) / l;
  const int t = i & 1023;
  const int bh = i >> 10;
  const int b = bh >> 3, h = bh & 7;
  diag[(((size_t)(b * 1024 + t)) << 3) + h] = dg;
}

// ---------------------------------------------------------------------------
// Kernel C: out[tok, e] = b0[e] + sum_h diag[tok,h] * sum_d v2[b,h,tok,d] * W0[d*8+h, e]
// Split-K over h.  grid (4 = e-tile, 64 = tok-tile, 8 = h), 256 threads,
// 64x64 tile, 4x4 micro, d-chunk 16.
// ATOMIC=false: write partial[h][tok][e].  ATOMIC=true: atomicAdd into out.
// ---------------------------------------------------------------------------
template <bool ATOMIC>
__global__ __launch_bounds__(256) void av_gemm(
    const float* __restrict__ qkv2, const float* __restrict__ diag,
    const float* __restrict__ W0, float* __restrict__ partial,
    float* __restrict__ out) {
  __shared__ alignas(16) float As[16][68];  // [d][tok], pad
  __shared__ alignas(16) float Bs[16][64];  // [d][e]
  __shared__ float diagS[64];
  const int tid = threadIdx.x;
  const int ty = tid >> 4, tx = tid & 15;
  const int e0 = blockIdx.x * 64;
  const int tok0 = blockIdx.y * 64;
  const int h = blockIdx.z;
  const int b = tok0 >> 10;
  const int n0 = tok0 & 1023;
  const float* Vbase = qkv2 + (size_t)((8 + b) * 8 + h) * (1024 * 256);  // seg 2

  if (tid < 64) diagS[tid] = diag[(((size_t)(tok0 + tid)) << 3) + h];
  __syncthreads();

  float acc[4][4] = {};
  for (int d0 = 0; d0 < 256; d0 += 16) {
    {  // A tile: 64 toks x 16 d, scaled by diag, transposed store
      const int row = tid >> 2;
      const int d4 = (tid & 3) << 2;
      const float4 v = *(const float4*)&Vbase[((size_t)(n0 + row) << 8) + d0 + d4];
      const float dg = diagS[row];
      As[d4 + 0][row] = v.x * dg; As[d4 + 1][row] = v.y * dg;
      As[d4 + 2][row] = v.z * dg; As[d4 + 3][row] = v.w * dg;
    }
    {  // B tile: 16 d x 64 e from W0 rows (d*8+h)
      const int kk = tid >> 4;
      const int e4 = (tid & 15) << 2;
      *(float4*)&Bs[kk][e4] =
          *(const float4*)&W0[((size_t)(d0 + kk) * 8 + h) * 256 + e0 + e4];
    }
    __syncthreads();
#pragma unroll
    for (int kk = 0; kk < 16; ++kk) {
      float a[4], bb[4];
      const float4 a_ = *(const float4*)&As[kk][ty * 4];
      a[0] = a_.x; a[1] = a_.y; a[2] = a_.z; a[3] = a_.w;
      const float4 b_ = *(const float4*)&Bs[kk][tx * 4];
      bb[0] = b_.x; bb[1] = b_.y; bb[2] = b_.z; bb[3] = b_.w;
#pragma unroll
      for (int i = 0; i < 4; ++i)
#pragma unroll
        for (int j = 0; j < 4; ++j) acc[i][j] += a[i] * bb[j];
    }
    __syncthreads();
  }

  if (ATOMIC) {
#pragma unroll
    for (int i = 0; i < 4; ++i)
#pragma unroll
      for (int j = 0; j < 4; ++j)
        atomicAdd(&out[(size_t)(tok0 + ty * 4 + i) * 256 + e0 + tx * 4 + j], acc[i][j]);
  } else {
#pragma unroll
    for (int i = 0; i < 4; ++i) {
      float4 v;
      v.x = acc[i][0]; v.y = acc[i][1]; v.z = acc[i][2]; v.w = acc[i][3];
      *(float4*)&partial[(size_t)h * 1048576 + (size_t)(tok0 + ty * 4 + i) * 256 +
                         e0 + tx * 4] = v;
    }
  }
}

// out init with bias (for atomic path).  grid (1024), 256 threads, float4 per thread.
__global__ void init_out(const float* __restrict__ b0, float* __restrict__ out) {
  const int i = blockIdx.x * 256 + threadIdx.x;  // 262144 float4 groups
  const int e0 = (i & 63) << 2;
  *(float4*)&out[(size_t)i * 4] = *(const float4*)&b0[e0];
}

// reduce split-K partials + bias.  grid (1024), 256 threads.
__global__ void reduce_out(const float* __restrict__ partial, const float* __restrict__ b0,
                           float* __restrict__ out) {
  const int i = blockIdx.x * 256 + threadIdx.x;  // 262144 float4 groups
  const int e0 = (i & 63) << 2;
  float4 a = *(const float4*)&b0[e0];
#pragma unroll
  for (int h = 0; h < 8; ++h) {
    const float4 p = *(const float4*)&partial[(size_t)h * 1048576 + (size_t)i * 4];
    a.x += p.x; a.y += p.y; a.z += p.z; a.w += p.w;
  }
  *(float4*)&out[(size_t)i * 4] = a;
}

extern "C" void kernel_launch(void* const* d_in, const int* in_sizes, int n_in,
                              void* d_out, int out_size, void* d_ws, size_t ws_size,
                              hipStream_t stream) {
  const float* x    = (const float*)d_in[0];
  const float* Wqkv = (const float*)d_in[1];
  const float* bqkv = (const float*)d_in[2];
  const float* W0   = (const float*)d_in[3];
  const float* b0   = (const float*)d_in[4];
  float* out = (float*)d_out;
  float* ws = (float*)d_ws;

  float* qkv2    = ws;                       // 25165824
  float* pm      = qkv2 + 3 * SEGSZ;         // 131072
  float* pl      = pm + 131072;              // 131072
  float* sd      = pl + 131072;              // 32768
  float* diag    = sd + 32768;               // 32768
  float* partial = diag + 32768;             // 8388608 (optional)

  const size_t need_full =
      (size_t)(3 * SEGSZ + 131072 * 2 + 32768 * 2 + 8388608) * sizeof(float);
  const bool full = ws_size >= need_full;

  qkv_gemm<<<dim3(48, 64), 256, 0, stream>>>(x, Wqkv, bqkv, qkv2);
  scores_kernel<<<dim3(32, 8, 4), 256, 0, stream>>>(qkv2, pm, pl, sd);
  merge_diag<<<128, 256, 0, stream>>>(pm, pl, sd, diag);
  if (full) {
    av_gemm<false><<<dim3(4, 64, 8), 256, 0, stream>>>(qkv2, diag, W0, partial, out);
    reduce_out<<<1024, 256, 0, stream>>>(partial, b0, out);
  } else {
    init_out<<<1024, 256, 0, stream>>>(b0, out);
    av_gemm<true><<<dim3(4, 64, 8), 256, 0, stream>>>(qkv2, diag, W0, nullptr, out);
  }
}

// Round 2
// 334.314 us; speedup vs baseline: 1.5658x; 1.5658x over previous
//
#include <hip/hip_runtime.h>

// Problem constants: B=4, N=1024, D=256, H=8
// Workspace layout:
//   v2   : [B][H][N][D] fp32      = 8388608 floats   (v, transposed layout)
//   qb   : [B][H][N][D] bf16      = 8388608 ushorts  (q * 2^-4, pre-scaled)
//   kb   : [B][H][N][D] bf16      = 8388608 ushorts
//   pm   : [B*H][N][8]  fp32      = 262144           (partial max, 8 n-tiles)
//   pl   : [B*H][N][8]  fp32      = 262144           (partial sum-exp)
//   sd   : [B*H][N]     fp32      = 32768            (scaled diagonal score)
//   diag : [B*N][H]     fp32      = 32768
//   partial: [8][4096][256] fp32  = 8388608          (split-K out GEMM, optional)

#define SEGSZ 8388608

typedef short v8s __attribute__((ext_vector_type(8)));
typedef float v4f __attribute__((ext_vector_type(4)));

__device__ __forceinline__ ushort f2bf(float v) {
  union { float f; unsigned u; } x; x.f = v;
  const unsigned r = x.u + 0x7fff + ((x.u >> 16) & 1);   // RTNE
  return (ushort)(r >> 16);
}

#define GLOAD_LDS16(g, l)                                            \
  __builtin_amdgcn_global_load_lds(                                  \
      (const __attribute__((address_space(1))) void*)(g),            \
      (__attribute__((address_space(3))) void*)(l), 16, 0, 0)

// ---------------------------------------------------------------------------
// Kernel A: qkv = x @ Wqkv + bqkv; scatter q->qb (bf16, *2^-4), k->kb (bf16),
// v->v2 (fp32), all in [b][h][n][d] layout.  grid (48, 64), 256 thr.
// ---------------------------------------------------------------------------
__global__ __launch_bounds__(256) void qkv_gemm(
    const float* __restrict__ X, const float* __restrict__ W,
    const float* __restrict__ bias, ushort* __restrict__ qb,
    ushort* __restrict__ kb, float* __restrict__ v2) {
  __shared__ alignas(16) float Xs[16][68];
  __shared__ alignas(16) float Ws[16][128];
  const int tid = threadIdx.x;
  const int ty = tid >> 4, tx = tid & 15;
  const int r0 = blockIdx.y * 64;
  const int c0 = blockIdx.x * 128;

  float acc[4][8] = {};

  for (int k0 = 0; k0 < 256; k0 += 16) {
    {
      const int row = tid >> 2;
      const int k4 = (tid & 3) << 2;
      const float4 v = *(const float4*)&X[(size_t)(r0 + row) * 256 + k0 + k4];
      Xs[k4 + 0][row] = v.x; Xs[k4 + 1][row] = v.y;
      Xs[k4 + 2][row] = v.z; Xs[k4 + 3][row] = v.w;
    }
    {
      int idx = tid;
      int kk = idx >> 5, c4 = (idx & 31) << 2;
      *(float4*)&Ws[kk][c4] = *(const float4*)&W[(size_t)(k0 + kk) * 6144 + c0 + c4];
      idx = tid + 256;
      kk = idx >> 5; c4 = (idx & 31) << 2;
      *(float4*)&Ws[kk][c4] = *(const float4*)&W[(size_t)(k0 + kk) * 6144 + c0 + c4];
    }
    __syncthreads();
#pragma unroll
    for (int kk = 0; kk < 16; ++kk) {
      float a[4], bb[8];
      {
        const float4 t0_ = *(const float4*)&Xs[kk][ty * 4];
        a[0] = t0_.x; a[1] = t0_.y; a[2] = t0_.z; a[3] = t0_.w;
        const float4 b0_ = *(const float4*)&Ws[kk][tx * 4];
        const float4 b1_ = *(const float4*)&Ws[kk][64 + tx * 4];
        bb[0] = b0_.x; bb[1] = b0_.y; bb[2] = b0_.z; bb[3] = b0_.w;
        bb[4] = b1_.x; bb[5] = b1_.y; bb[6] = b1_.z; bb[7] = b1_.w;
      }
#pragma unroll
      for (int i = 0; i < 4; ++i)
#pragma unroll
        for (int j = 0; j < 8; ++j) acc[i][j] += a[i] * bb[j];
    }
    __syncthreads();
  }

#pragma unroll
  for (int i = 0; i < 4; ++i) {
    const int r = r0 + ty * 4 + i;
#pragma unroll
    for (int j = 0; j < 8; ++j) {
      const int c = c0 + ((j < 4) ? (tx * 4 + j) : (64 + tx * 4 + (j - 4)));
      const float val = acc[i][j] + bias[c];
      const int g = r * 3 + (c >> 11);
      const int dh = c & 2047;
      const int d = dh >> 3, h = dh & 7;
      const int seg = g >> 12;
      const int tok = g & 4095;
      const size_t dst =
          ((((size_t)(tok >> 10) * 8 + h) * 1024 + (tok & 1023)) << 8) + d;
      if (seg == 0)      qb[dst] = f2bf(val * 0.0625f);
      else if (seg == 1) kb[dst] = f2bf(val);
      else               v2[dst] = val;
    }
  }
}

// ---------------------------------------------------------------------------
// Kernel B: bf16 MFMA score stats.  S = Qs·Ks^T per (b,h); softmax over rows n,
// stats per column t.  Block: 128(n) x 128(t) S-tile, 4 waves, each 64x64,
// 16x16x32 bf16 MFMA, BK=32, global_load_lds width-16 staging.
// grid (8 = t-tile, 8 = n-tile, 32 = b*h), 256 threads.
// ---------------------------------------------------------------------------
__global__ __launch_bounds__(256) void scores_mfma(
    const ushort* __restrict__ qb, const ushort* __restrict__ kb,
    float* __restrict__ pm, float* __restrict__ pl, float* __restrict__ sd_ws) {
  __shared__ ushort Qs[128 * 32];
  __shared__ ushort Ks[128 * 32];
  __shared__ float redM[2][2][64];
  __shared__ float redL[2][2][64];

  const int tid = threadIdx.x;
  const int wave = tid >> 6, lane = tid & 63;
  const int quad = lane >> 4, l15 = lane & 15;
  const int tt0 = blockIdx.x * 128;   // t (column) block
  const int nn0 = blockIdx.y * 128;   // n (row) block
  const int bh = blockIdx.z;
  const ushort* Qg = qb + (size_t)bh * (1024 * 256);
  const ushort* Kg = kb + (size_t)bh * (1024 * 256);

  const int wr = (wave >> 1) * 64;    // wave's row quadrant
  const int wc = (wave & 1) * 64;     // wave's col quadrant

  v4f acc[4][4] = {};                 // [ri][ci]

  for (int d0 = 0; d0 < 256; d0 += 32) {
    // stage 128x32 Q and K tiles; each wave: 32 rows each via 2+2 lds-loads
#pragma unroll
    for (int half = 0; half < 2; ++half) {
      const int rr = wave * 32 + half * 16;           // wave-uniform
      const int row = rr + (lane >> 2);
      const int gcol = d0 + (lane & 3) * 8;
      GLOAD_LDS16(Qg + (size_t)(nn0 + row) * 256 + gcol, &Qs[rr * 32]);
      GLOAD_LDS16(Kg + (size_t)(tt0 + row) * 256 + gcol, &Ks[rr * 32]);
    }
    __syncthreads();

    v8s aF[4], bF[4];
#pragma unroll
    for (int i = 0; i < 4; ++i) {
      aF[i] = *(const v8s*)&Qs[(wr + i * 16 + l15) * 32 + quad * 8];
      bF[i] = *(const v8s*)&Ks[(wc + i * 16 + l15) * 32 + quad * 8];
    }
#pragma unroll
    for (int ri = 0; ri < 4; ++ri)
#pragma unroll
      for (int ci = 0; ci < 4; ++ci)
        acc[ri][ci] =
            __builtin_amdgcn_mfma_f32_16x16x32_bf16(aF[ri], bF[ci], acc[ri][ci], 0, 0, 0);
    __syncthreads();
  }

  // ---- column stats.  C layout: col = l15, row = quad*4 + reg ----
  float mloc[4];
#pragma unroll
  for (int ci = 0; ci < 4; ++ci) {
    float m = acc[0][ci][0];
#pragma unroll
    for (int ri = 0; ri < 4; ++ri)
#pragma unroll
      for (int rg = 0; rg < 4; ++rg) m = fmaxf(m, acc[ri][ci][rg]);
    m = fmaxf(m, __shfl_xor(m, 16, 64));
    m = fmaxf(m, __shfl_xor(m, 32, 64));
    mloc[ci] = m;                      // max over this wave's 64 rows
  }
  if (quad == 0) {
#pragma unroll
    for (int ci = 0; ci < 4; ++ci)
      redM[wave & 1][wave >> 1][ci * 16 + l15] = mloc[ci];
  }
  __syncthreads();
  float mfull[4], lsum[4];
#pragma unroll
  for (int ci = 0; ci < 4; ++ci) {
    const float m = fmaxf(mloc[ci], redM[wave & 1][1 - (wave >> 1)][ci * 16 + l15]);
    mfull[ci] = m;
    float s = 0.f;
#pragma unroll
    for (int ri = 0; ri < 4; ++ri)
#pragma unroll
      for (int rg = 0; rg < 4; ++rg) s += __expf(acc[ri][ci][rg] - m);
    s += __shfl_xor(s, 16, 64);
    s += __shfl_xor(s, 32, 64);
    lsum[ci] = s;
  }
  if (quad == 0) {
#pragma unroll
    for (int ci = 0; ci < 4; ++ci)
      redL[wave & 1][wave >> 1][ci * 16 + l15] = lsum[ci];
  }
  __syncthreads();
  if ((wave >> 1) == 0 && quad == 0) {
#pragma unroll
    for (int ci = 0; ci < 4; ++ci) {
      const int t = tt0 + (wave & 1) * 64 + ci * 16 + l15;
      const float l = lsum[ci] + redL[wave & 1][1][ci * 16 + l15];
      const size_t idx = ((size_t)bh * 1024 + t) * 8 + blockIdx.y;
      pm[idx] = mfull[ci];
      pl[idx] = l;
    }
  }

  // ---- diagonal capture (only diagonal blocks; waves 0 and 3) ----
  if (tt0 == nn0 && (wave == 0 || wave == 3) && quad == (l15 >> 2)) {
#pragma unroll
    for (int ri = 0; ri < 4; ++ri) {
      const int t = tt0 + (wave & 1) * 64 + ri * 16 + l15;
      sd_ws[(size_t)bh * 1024 + t] = acc[ri][ri][l15 & 3];
    }
  }
}

// ---------------------------------------------------------------------------
// Merge partial stats (8 chunks) -> diag[b*N + t][h].  grid (128), 256 thr.
// ---------------------------------------------------------------------------
__global__ void merge_diag(const float* __restrict__ pm, const float* __restrict__ pl,
                           const float* __restrict__ sd, float* __restrict__ diag) {
  const int i = blockIdx.x * 256 + threadIdx.x;  // (b*8+h)*1024 + t
  float m = -1e30f;
#pragma unroll
  for (int c = 0; c < 8; ++c) m = fmaxf(m, pm[(size_t)i * 8 + c]);
  float l = 0.f;
#pragma unroll
  for (int c = 0; c < 8; ++c)
    l += pl[(size_t)i * 8 + c] * __expf(pm[(size_t)i * 8 + c] - m);
  const float dg = __expf(sd[i] - m) / l;
  const int t = i & 1023;
  const int bh = i >> 10;
  const int b = bh >> 3, h = bh & 7;
  diag[(((size_t)(b * 1024 + t)) << 3) + h] = dg;
}

// ---------------------------------------------------------------------------
// Kernel C: out[tok, e] = b0[e] + sum_h diag[tok,h] * sum_d v2[b,h,tok,d]*W0[d*8+h, e]
// Split-K over h.  grid (4, 64, 8), 256 thr, 64x64 tile, 4x4 micro.
// ---------------------------------------------------------------------------
template <bool ATOMIC>
__global__ __launch_bounds__(256) void av_gemm(
    const float* __restrict__ v2, const float* __restrict__ diag,
    const float* __restrict__ W0, float* __restrict__ partial,
    float* __restrict__ out) {
  __shared__ alignas(16) float As[16][68];
  __shared__ alignas(16) float Bs[16][64];
  __shared__ float diagS[64];
  const int tid = threadIdx.x;
  const int ty = tid >> 4, tx = tid & 15;
  const int e0 = blockIdx.x * 64;
  const int tok0 = blockIdx.y * 64;
  const int h = blockIdx.z;
  const int b = tok0 >> 10;
  const int n0 = tok0 & 1023;
  const float* Vbase = v2 + (size_t)(b * 8 + h) * (1024 * 256);

  if (tid < 64) diagS[tid] = diag[(((size_t)(tok0 + tid)) << 3) + h];
  __syncthreads();

  float acc[4][4] = {};
  for (int d0 = 0; d0 < 256; d0 += 16) {
    {
      const int row = tid >> 2;
      const int d4 = (tid & 3) << 2;
      const float4 v = *(const float4*)&Vbase[((size_t)(n0 + row) << 8) + d0 + d4];
      const float dg = diagS[row];
      As[d4 + 0][row] = v.x * dg; As[d4 + 1][row] = v.y * dg;
      As[d4 + 2][row] = v.z * dg; As[d4 + 3][row] = v.w * dg;
    }
    {
      const int kk = tid >> 4;
      const int e4 = (tid & 15) << 2;
      *(float4*)&Bs[kk][e4] =
          *(const float4*)&W0[((size_t)(d0 + kk) * 8 + h) * 256 + e0 + e4];
    }
    __syncthreads();
#pragma unroll
    for (int kk = 0; kk < 16; ++kk) {
      float a[4], bb[4];
      const float4 a_ = *(const float4*)&As[kk][ty * 4];
      a[0] = a_.x; a[1] = a_.y; a[2] = a_.z; a[3] = a_.w;
      const float4 b_ = *(const float4*)&Bs[kk][tx * 4];
      bb[0] = b_.x; bb[1] = b_.y; bb[2] = b_.z; bb[3] = b_.w;
#pragma unroll
      for (int i = 0; i < 4; ++i)
#pragma unroll
        for (int j = 0; j < 4; ++j) acc[i][j] += a[i] * bb[j];
    }
    __syncthreads();
  }

  if (ATOMIC) {
#pragma unroll
    for (int i = 0; i < 4; ++i)
#pragma unroll
      for (int j = 0; j < 4; ++j)
        atomicAdd(&out[(size_t)(tok0 + ty * 4 + i) * 256 + e0 + tx * 4 + j], acc[i][j]);
  } else {
#pragma unroll
    for (int i = 0; i < 4; ++i) {
      float4 v;
      v.x = acc[i][0]; v.y = acc[i][1]; v.z = acc[i][2]; v.w = acc[i][3];
      *(float4*)&partial[(size_t)h * 1048576 + (size_t)(tok0 + ty * 4 + i) * 256 +
                         e0 + tx * 4] = v;
    }
  }
}

__global__ void init_out(const float* __restrict__ b0, float* __restrict__ out) {
  const int i = blockIdx.x * 256 + threadIdx.x;
  const int e0 = (i & 63) << 2;
  *(float4*)&out[(size_t)i * 4] = *(const float4*)&b0[e0];
}

__global__ void reduce_out(const float* __restrict__ partial, const float* __restrict__ b0,
                           float* __restrict__ out) {
  const int i = blockIdx.x * 256 + threadIdx.x;
  const int e0 = (i & 63) << 2;
  float4 a = *(const float4*)&b0[e0];
#pragma unroll
  for (int h = 0; h < 8; ++h) {
    const float4 p = *(const float4*)&partial[(size_t)h * 1048576 + (size_t)i * 4];
    a.x += p.x; a.y += p.y; a.z += p.z; a.w += p.w;
  }
  *(float4*)&out[(size_t)i * 4] = a;
}

extern "C" void kernel_launch(void* const* d_in, const int* in_sizes, int n_in,
                              void* d_out, int out_size, void* d_ws, size_t ws_size,
                              hipStream_t stream) {
  const float* x    = (const float*)d_in[0];
  const float* Wqkv = (const float*)d_in[1];
  const float* bqkv = (const float*)d_in[2];
  const float* W0   = (const float*)d_in[3];
  const float* b0   = (const float*)d_in[4];
  float* out = (float*)d_out;
  float* ws = (float*)d_ws;

  float*  v2   = ws;                               // 8388608 f
  ushort* qb   = (ushort*)(v2 + SEGSZ);            // 8388608 us
  ushort* kb   = qb + SEGSZ;                       // 8388608 us
  float*  pm   = (float*)(kb + SEGSZ);             // 262144 f
  float*  pl   = pm + 262144;                      // 262144 f
  float*  sd   = pl + 262144;                      // 32768 f
  float*  diag = sd + 32768;                       // 32768 f
  float*  partial = diag + 32768;                  // 8388608 f

  const size_t need_full = (size_t)(SEGSZ * 4) /*v2*/ + (size_t)(SEGSZ * 4) /*qb+kb*/ +
                           (262144 * 2 + 32768 * 2 + SEGSZ) * sizeof(float);
  const bool full = ws_size >= need_full;

  qkv_gemm<<<dim3(48, 64), 256, 0, stream>>>(x, Wqkv, bqkv, qb, kb, v2);
  scores_mfma<<<dim3(8, 8, 32), 256, 0, stream>>>(qb, kb, pm, pl, sd);
  merge_diag<<<128, 256, 0, stream>>>(pm, pl, sd, diag);
  if (full) {
    av_gemm<false><<<dim3(4, 64, 8), 256, 0, stream>>>(v2, diag, W0, partial, out);
    reduce_out<<<1024, 256, 0, stream>>>(partial, b0, out);
  } else {
    init_out<<<1024, 256, 0, stream>>>(b0, out);
    av_gemm<true><<<dim3(4, 64, 8), 256, 0, stream>>>(v2, diag, W0, nullptr, out);
  }
}

// Round 3
// 303.181 us; speedup vs baseline: 1.7266x; 1.1027x over previous
//
#include <hip/hip_runtime.h>

// Problem constants: B=4, N=1024, D=256, H=8
// Workspace (in order):
//   v2   : [B][H][N][D] fp32      = 8388608 floats
//   qb   : [B][H][N][D] bf16      = 8388608 ushorts  (q * 2^-4 pre-scaled)
//   kb   : [B][H][N][D] bf16      = 8388608 ushorts
//   pm   : [B*H][N][8]  fp32      = 262144
//   pl   : [B*H][N][8]  fp32      = 262144
//   sd   : [B*H][N]     fp32      = 32768
//   diag : [B*N][H]     fp32      = 32768
//   xh,xl: [4096][256]  bf16      = 1048576 each     (x split hi/lo)
//   whT,wlT: [6144][256] bf16     = 1572864 each     (Wqkv split, TRANSPOSED [n][k])
//   partial: [8][4096][256] fp32  = 8388608          (split-K out GEMM, optional)

#define SEGSZ 8388608

typedef short v8s __attribute__((ext_vector_type(8)));
typedef float v4f __attribute__((ext_vector_type(4)));

__device__ __forceinline__ ushort f2bf(float v) {
  union { float f; unsigned u; } x; x.f = v;
  const unsigned r = x.u + 0x7fff + ((x.u >> 16) & 1);   // RTNE
  return (ushort)(r >> 16);
}
__device__ __forceinline__ float bf2f(ushort v) {
  union { unsigned u; float f; } x; x.u = ((unsigned)v) << 16;
  return x.f;
}

#define GLOAD_LDS16(g, l)                                            \
  __builtin_amdgcn_global_load_lds(                                  \
      (const __attribute__((address_space(1))) void*)(g),            \
      (__attribute__((address_space(3))) void*)(l), 16, 0, 0)

// ---------------------------------------------------------------------------
// Split x (fp32) into bf16 hi/lo.  grid (1024), 256 thr, 4 elems/thr.
// ---------------------------------------------------------------------------
__global__ void conv_x(const float* __restrict__ X, ushort* __restrict__ xh,
                       ushort* __restrict__ xl) {
  const size_t i = ((size_t)blockIdx.x * 256 + threadIdx.x) * 4;
  const float4 v = *(const float4*)&X[i];
  ushort h0 = f2bf(v.x), h1 = f2bf(v.y), h2 = f2bf(v.z), h3 = f2bf(v.w);
  ushort4 hv = {h0, h1, h2, h3};
  ushort4 lv = {f2bf(v.x - bf2f(h0)), f2bf(v.y - bf2f(h1)),
                f2bf(v.z - bf2f(h2)), f2bf(v.w - bf2f(h3))};
  *(ushort4*)&xh[i] = hv;
  *(ushort4*)&xl[i] = lv;
}

// ---------------------------------------------------------------------------
// Split + transpose Wqkv [256][6144] -> whT/wlT [6144][256] bf16.
// grid (96, 4): 64(n) x 64(k) tile, 256 thr, LDS transpose.
// ---------------------------------------------------------------------------
__global__ __launch_bounds__(256) void conv_wT(const float* __restrict__ W,
                                               ushort* __restrict__ whT,
                                               ushort* __restrict__ wlT) {
  __shared__ float T[64][65];
  const int tid = threadIdx.x;
  const int n0 = blockIdx.x * 64;
  const int k0 = blockIdx.y * 64;
  {  // read 64(k) x 64(n), coalesced along n
    const int row = tid >> 2;           // k within tile
    const int c0 = (tid & 3) * 16;      // n within tile
#pragma unroll
    for (int j = 0; j < 16; j += 4) {
      const float4 v = *(const float4*)&W[(size_t)(k0 + row) * 6144 + n0 + c0 + j];
      T[row][c0 + j + 0] = v.x; T[row][c0 + j + 1] = v.y;
      T[row][c0 + j + 2] = v.z; T[row][c0 + j + 3] = v.w;
    }
  }
  __syncthreads();
  {  // write 64(n) x 64(k), coalesced along k
    const int nn = tid >> 2;
    const int kk0 = (tid & 3) * 16;
    ushort hv[16], lv[16];
#pragma unroll
    for (int j = 0; j < 16; ++j) {
      const float v = T[kk0 + j][nn];
      hv[j] = f2bf(v);
      lv[j] = f2bf(v - bf2f(hv[j]));
    }
    const size_t base = (size_t)(n0 + nn) * 256 + k0 + kk0;
#pragma unroll
    for (int j = 0; j < 16; j += 8) {
      *(v8s*)&whT[base + j] = *(v8s*)&hv[j];
      *(v8s*)&wlT[base + j] = *(v8s*)&lv[j];
    }
  }
}

// ---------------------------------------------------------------------------
// Kernel A: qkv = x @ Wqkv + bqkv via bf16x3 MFMA (xh*wh + xl*wh + xh*wl).
// 128x128 tile, 4 waves x (64x64), BK=32, K_eff=768.  grid (48, 32), 256 thr.
// Epilogue scatters q->qb (bf16 *2^-4), k->kb (bf16), v->v2 (fp32).
// ---------------------------------------------------------------------------
__global__ __launch_bounds__(256) void qkv_mfma(
    const ushort* __restrict__ xh, const ushort* __restrict__ xl,
    const ushort* __restrict__ whT, const ushort* __restrict__ wlT,
    const float* __restrict__ bias, ushort* __restrict__ qb,
    ushort* __restrict__ kb, float* __restrict__ v2) {
  __shared__ ushort As[128 * 32];
  __shared__ ushort Bs[128 * 32];
  const int tid = threadIdx.x;
  const int wave = tid >> 6, lane = tid & 63;
  const int quad = lane >> 4, l15 = lane & 15;
  const int c0 = blockIdx.x * 128;    // col block in 6144
  const int r0 = blockIdx.y * 128;    // row block in 4096
  const int wr = (wave >> 1) * 64;
  const int wc = (wave & 1) * 64;

  v4f acc[4][4] = {};                 // [ri][ci]

  for (int pass = 0; pass < 3; ++pass) {
    const ushort* Ap = (pass == 1) ? xl : xh;
    const ushort* Bp = (pass == 2) ? wlT : whT;
    for (int d0 = 0; d0 < 256; d0 += 32) {
#pragma unroll
      for (int half = 0; half < 2; ++half) {
        const int rr = wave * 32 + half * 16;
        const int row = rr + (lane >> 2);
        const int gcol = d0 + (lane & 3) * 8;
        GLOAD_LDS16(Ap + (size_t)(r0 + row) * 256 + gcol, &As[rr * 32]);
        GLOAD_LDS16(Bp + (size_t)(c0 + row) * 256 + gcol, &Bs[rr * 32]);
      }
      __syncthreads();

      v8s aF[4], bF[4];
#pragma unroll
      for (int i = 0; i < 4; ++i) {
        aF[i] = *(const v8s*)&As[(wr + i * 16 + l15) * 32 + quad * 8];
        bF[i] = *(const v8s*)&Bs[(wc + i * 16 + l15) * 32 + quad * 8];
      }
#pragma unroll
      for (int ri = 0; ri < 4; ++ri)
#pragma unroll
        for (int ci = 0; ci < 4; ++ci)
          acc[ri][ci] = __builtin_amdgcn_mfma_f32_16x16x32_bf16(
              aF[ri], bF[ci], acc[ri][ci], 0, 0, 0);
      __syncthreads();
    }
  }

  // Epilogue: C layout col=l15, row=quad*4+reg.  Scatter to [b][h][n][d].
#pragma unroll
  for (int ci = 0; ci < 4; ++ci) {
    const int c = c0 + wc + ci * 16 + l15;
    const float bv = bias[c];
    const int d = (c & 2047) >> 3, h = c & 7;
    const int cseg = c >> 11;
#pragma unroll
    for (int ri = 0; ri < 4; ++ri)
#pragma unroll
      for (int rg = 0; rg < 4; ++rg) {
        const int r = r0 + wr + ri * 16 + quad * 4 + rg;
        const float val = acc[ri][ci][rg] + bv;
        const int g = r * 3 + cseg;
        const int seg = g >> 12;
        const int tok = g & 4095;
        const size_t dst =
            ((((size_t)(tok >> 10) * 8 + h) * 1024 + (tok & 1023)) << 8) + d;
        if (seg == 0)      qb[dst] = f2bf(val * 0.0625f);
        else if (seg == 1) kb[dst] = f2bf(val);
        else               v2[dst] = val;
      }
  }
}

// ---------------------------------------------------------------------------
// Kernel B: bf16 MFMA score stats (unchanged from R2, verified).
// grid (8, 8, 32), 256 threads.
// ---------------------------------------------------------------------------
__global__ __launch_bounds__(256) void scores_mfma(
    const ushort* __restrict__ qb, const ushort* __restrict__ kb,
    float* __restrict__ pm, float* __restrict__ pl, float* __restrict__ sd_ws) {
  __shared__ ushort Qs[128 * 32];
  __shared__ ushort Ks[128 * 32];
  __shared__ float redM[2][2][64];
  __shared__ float redL[2][2][64];

  const int tid = threadIdx.x;
  const int wave = tid >> 6, lane = tid & 63;
  const int quad = lane >> 4, l15 = lane & 15;
  const int tt0 = blockIdx.x * 128;
  const int nn0 = blockIdx.y * 128;
  const int bh = blockIdx.z;
  const ushort* Qg = qb + (size_t)bh * (1024 * 256);
  const ushort* Kg = kb + (size_t)bh * (1024 * 256);

  const int wr = (wave >> 1) * 64;
  const int wc = (wave & 1) * 64;

  v4f acc[4][4] = {};

  for (int d0 = 0; d0 < 256; d0 += 32) {
#pragma unroll
    for (int half = 0; half < 2; ++half) {
      const int rr = wave * 32 + half * 16;
      const int row = rr + (lane >> 2);
      const int gcol = d0 + (lane & 3) * 8;
      GLOAD_LDS16(Qg + (size_t)(nn0 + row) * 256 + gcol, &Qs[rr * 32]);
      GLOAD_LDS16(Kg + (size_t)(tt0 + row) * 256 + gcol, &Ks[rr * 32]);
    }
    __syncthreads();

    v8s aF[4], bF[4];
#pragma unroll
    for (int i = 0; i < 4; ++i) {
      aF[i] = *(const v8s*)&Qs[(wr + i * 16 + l15) * 32 + quad * 8];
      bF[i] = *(const v8s*)&Ks[(wc + i * 16 + l15) * 32 + quad * 8];
    }
#pragma unroll
    for (int ri = 0; ri < 4; ++ri)
#pragma unroll
      for (int ci = 0; ci < 4; ++ci)
        acc[ri][ci] =
            __builtin_amdgcn_mfma_f32_16x16x32_bf16(aF[ri], bF[ci], acc[ri][ci], 0, 0, 0);
    __syncthreads();
  }

  float mloc[4];
#pragma unroll
  for (int ci = 0; ci < 4; ++ci) {
    float m = acc[0][ci][0];
#pragma unroll
    for (int ri = 0; ri < 4; ++ri)
#pragma unroll
      for (int rg = 0; rg < 4; ++rg) m = fmaxf(m, acc[ri][ci][rg]);
    m = fmaxf(m, __shfl_xor(m, 16, 64));
    m = fmaxf(m, __shfl_xor(m, 32, 64));
    mloc[ci] = m;
  }
  if (quad == 0) {
#pragma unroll
    for (int ci = 0; ci < 4; ++ci)
      redM[wave & 1][wave >> 1][ci * 16 + l15] = mloc[ci];
  }
  __syncthreads();
  float mfull[4], lsum[4];
#pragma unroll
  for (int ci = 0; ci < 4; ++ci) {
    const float m = fmaxf(mloc[ci], redM[wave & 1][1 - (wave >> 1)][ci * 16 + l15]);
    mfull[ci] = m;
    float s = 0.f;
#pragma unroll
    for (int ri = 0; ri < 4; ++ri)
#pragma unroll
      for (int rg = 0; rg < 4; ++rg) s += __expf(acc[ri][ci][rg] - m);
    s += __shfl_xor(s, 16, 64);
    s += __shfl_xor(s, 32, 64);
    lsum[ci] = s;
  }
  if (quad == 0) {
#pragma unroll
    for (int ci = 0; ci < 4; ++ci)
      redL[wave & 1][wave >> 1][ci * 16 + l15] = lsum[ci];
  }
  __syncthreads();
  if ((wave >> 1) == 0 && quad == 0) {
#pragma unroll
    for (int ci = 0; ci < 4; ++ci) {
      const int t = tt0 + (wave & 1) * 64 + ci * 16 + l15;
      const float l = lsum[ci] + redL[wave & 1][1][ci * 16 + l15];
      const size_t idx = ((size_t)bh * 1024 + t) * 8 + blockIdx.y;
      pm[idx] = mfull[ci];
      pl[idx] = l;
    }
  }

  if (tt0 == nn0 && (wave == 0 || wave == 3) && quad == (l15 >> 2)) {
#pragma unroll
    for (int ri = 0; ri < 4; ++ri) {
      const int t = tt0 + (wave & 1) * 64 + ri * 16 + l15;
      sd_ws[(size_t)bh * 1024 + t] = acc[ri][ri][l15 & 3];
    }
  }
}

// ---------------------------------------------------------------------------
__global__ void merge_diag(const float* __restrict__ pm, const float* __restrict__ pl,
                           const float* __restrict__ sd, float* __restrict__ diag) {
  const int i = blockIdx.x * 256 + threadIdx.x;
  float m = -1e30f;
#pragma unroll
  for (int c = 0; c < 8; ++c) m = fmaxf(m, pm[(size_t)i * 8 + c]);
  float l = 0.f;
#pragma unroll
  for (int c = 0; c < 8; ++c)
    l += pl[(size_t)i * 8 + c] * __expf(pm[(size_t)i * 8 + c] - m);
  const float dg = __expf(sd[i] - m) / l;
  const int t = i & 1023;
  const int bh = i >> 10;
  const int b = bh >> 3, h = bh & 7;
  diag[(((size_t)(b * 1024 + t)) << 3) + h] = dg;
}

// ---------------------------------------------------------------------------
template <bool ATOMIC>
__global__ __launch_bounds__(256) void av_gemm(
    const float* __restrict__ v2, const float* __restrict__ diag,
    const float* __restrict__ W0, float* __restrict__ partial,
    float* __restrict__ out) {
  __shared__ alignas(16) float As[16][68];
  __shared__ alignas(16) float Bs[16][64];
  __shared__ float diagS[64];
  const int tid = threadIdx.x;
  const int ty = tid >> 4, tx = tid & 15;
  const int e0 = blockIdx.x * 64;
  const int tok0 = blockIdx.y * 64;
  const int h = blockIdx.z;
  const int b = tok0 >> 10;
  const int n0 = tok0 & 1023;
  const float* Vbase = v2 + (size_t)(b * 8 + h) * (1024 * 256);

  if (tid < 64) diagS[tid] = diag[(((size_t)(tok0 + tid)) << 3) + h];
  __syncthreads();

  float acc[4][4] = {};
  for (int d0 = 0; d0 < 256; d0 += 16) {
    {
      const int row = tid >> 2;
      const int d4 = (tid & 3) << 2;
      const float4 v = *(const float4*)&Vbase[((size_t)(n0 + row) << 8) + d0 + d4];
      const float dg = diagS[row];
      As[d4 + 0][row] = v.x * dg; As[d4 + 1][row] = v.y * dg;
      As[d4 + 2][row] = v.z * dg; As[d4 + 3][row] = v.w * dg;
    }
    {
      const int kk = tid >> 4;
      const int e4 = (tid & 15) << 2;
      *(float4*)&Bs[kk][e4] =
          *(const float4*)&W0[((size_t)(d0 + kk) * 8 + h) * 256 + e0 + e4];
    }
    __syncthreads();
#pragma unroll
    for (int kk = 0; kk < 16; ++kk) {
      float a[4], bb[4];
      const float4 a_ = *(const float4*)&As[kk][ty * 4];
      a[0] = a_.x; a[1] = a_.y; a[2] = a_.z; a[3] = a_.w;
      const float4 b_ = *(const float4*)&Bs[kk][tx * 4];
      bb[0] = b_.x; bb[1] = b_.y; bb[2] = b_.z; bb[3] = b_.w;
#pragma unroll
      for (int i = 0; i < 4; ++i)
#pragma unroll
        for (int j = 0; j < 4; ++j) acc[i][j] += a[i] * bb[j];
    }
    __syncthreads();
  }

  if (ATOMIC) {
#pragma unroll
    for (int i = 0; i < 4; ++i)
#pragma unroll
      for (int j = 0; j < 4; ++j)
        atomicAdd(&out[(size_t)(tok0 + ty * 4 + i) * 256 + e0 + tx * 4 + j], acc[i][j]);
  } else {
#pragma unroll
    for (int i = 0; i < 4; ++i) {
      float4 v;
      v.x = acc[i][0]; v.y = acc[i][1]; v.z = acc[i][2]; v.w = acc[i][3];
      *(float4*)&partial[(size_t)h * 1048576 + (size_t)(tok0 + ty * 4 + i) * 256 +
                         e0 + tx * 4] = v;
    }
  }
}

__global__ void init_out(const float* __restrict__ b0, float* __restrict__ out) {
  const int i = blockIdx.x * 256 + threadIdx.x;
  const int e0 = (i & 63) << 2;
  *(float4*)&out[(size_t)i * 4] = *(const float4*)&b0[e0];
}

__global__ void reduce_out(const float* __restrict__ partial, const float* __restrict__ b0,
                           float* __restrict__ out) {
  const int i = blockIdx.x * 256 + threadIdx.x;
  const int e0 = (i & 63) << 2;
  float4 a = *(const float4*)&b0[e0];
#pragma unroll
  for (int h = 0; h < 8; ++h) {
    const float4 p = *(const float4*)&partial[(size_t)h * 1048576 + (size_t)i * 4];
    a.x += p.x; a.y += p.y; a.z += p.z; a.w += p.w;
  }
  *(float4*)&out[(size_t)i * 4] = a;
}

extern "C" void kernel_launch(void* const* d_in, const int* in_sizes, int n_in,
                              void* d_out, int out_size, void* d_ws, size_t ws_size,
                              hipStream_t stream) {
  const float* x    = (const float*)d_in[0];
  const float* Wqkv = (const float*)d_in[1];
  const float* bqkv = (const float*)d_in[2];
  const float* W0   = (const float*)d_in[3];
  const float* b0   = (const float*)d_in[4];
  float* out = (float*)d_out;
  float* ws = (float*)d_ws;

  float*  v2   = ws;                               // 8388608 f
  ushort* qb   = (ushort*)(v2 + SEGSZ);            // 8388608 us
  ushort* kb   = qb + SEGSZ;                       // 8388608 us
  float*  pm   = (float*)(kb + SEGSZ);             // 262144 f
  float*  pl   = pm + 262144;                      // 262144 f
  float*  sd   = pl + 262144;                      // 32768 f
  float*  diag = sd + 32768;                       // 32768 f
  ushort* xh   = (ushort*)(diag + 32768);          // 1048576 us
  ushort* xl   = xh + 1048576;                     // 1048576 us
  ushort* whT  = xl + 1048576;                     // 1572864 us
  ushort* wlT  = whT + 1572864;                    // 1572864 us
  float*  partial = (float*)(wlT + 1572864);       // 8388608 f (optional)

  const size_t need_full =
      (size_t)SEGSZ * 4 /*v2*/ + (size_t)SEGSZ * 4 /*qb+kb*/ +
      (size_t)(262144 * 2 + 32768 * 2) * 4 +
      (size_t)(1048576 * 2 + 1572864 * 2) * 2 + (size_t)SEGSZ * 4 /*partial*/;
  const bool full = ws_size >= need_full;

  conv_x<<<1024, 256, 0, stream>>>(x, xh, xl);
  conv_wT<<<dim3(96, 4), 256, 0, stream>>>(Wqkv, whT, wlT);
  qkv_mfma<<<dim3(48, 32), 256, 0, stream>>>(xh, xl, whT, wlT, bqkv, qb, kb, v2);
  scores_mfma<<<dim3(8, 8, 32), 256, 0, stream>>>(qb, kb, pm, pl, sd);
  merge_diag<<<128, 256, 0, stream>>>(pm, pl, sd, diag);
  if (full) {
    av_gemm<false><<<dim3(4, 64, 8), 256, 0, stream>>>(v2, diag, W0, partial, out);
    reduce_out<<<1024, 256, 0, stream>>>(partial, b0, out);
  } else {
    init_out<<<1024, 256, 0, stream>>>(b0, out);
    av_gemm<true><<<dim3(4, 64, 8), 256, 0, stream>>>(v2, diag, W0, nullptr, out);
  }
}

// Round 5
// 181.295 us; speedup vs baseline: 2.8874x; 1.6723x over previous
//
#include <hip/hip_runtime.h>

// Problem constants: B=4, N=1024, D=256, H=8
// All q/k/v stored bf16 in qkvb[seg][tok][h*256+d]  (tok-major, stride 2048).
// Wqkv is pre-transposed AND column-permuted: whT/wlT row p = seg*2048+h*256+d
// holds original column seg*2048+d*8+h, so the qkv epilogue writes coalesced.
// W0 is pre-transposed with the SAME k-permutation: w0T[e][h*256+d] = W0[d*8+h][e].

#define SEGSZ 8388608  // elements per q/k/v segment = 4096 tok * 2048

typedef short v8s __attribute__((ext_vector_type(8)));
typedef float v4f __attribute__((ext_vector_type(4)));

__device__ __forceinline__ ushort f2bf(float v) {
  union { float f; unsigned u; } x; x.f = v;
  const unsigned r = x.u + 0x7fff + ((x.u >> 16) & 1);   // RTNE
  return (ushort)(r >> 16);
}
__device__ __forceinline__ float bf2f(ushort v) {
  union { unsigned u; float f; } x; x.u = ((unsigned)v) << 16;
  return x.f;
}

#define GLOAD_LDS16(g, l)                                            \
  __builtin_amdgcn_global_load_lds(                                  \
      (const __attribute__((address_space(1))) void*)(g),            \
      (__attribute__((address_space(3))) void*)(l), 16, 0, 0)

// ---------------------------------------------------------------------------
// Split x (fp32) into bf16 hi/lo.  grid (1024), 256 thr, 4 elems/thr.
// ---------------------------------------------------------------------------
__global__ void conv_x(const float* __restrict__ X, ushort* __restrict__ xh,
                       ushort* __restrict__ xl) {
  const size_t i = ((size_t)blockIdx.x * 256 + threadIdx.x) * 4;
  const float4 v = *(const float4*)&X[i];
  ushort h0 = f2bf(v.x), h1 = f2bf(v.y), h2 = f2bf(v.z), h3 = f2bf(v.w);
  ushort4 hv = {h0, h1, h2, h3};
  ushort4 lv = {f2bf(v.x - bf2f(h0)), f2bf(v.y - bf2f(h1)),
                f2bf(v.z - bf2f(h2)), f2bf(v.w - bf2f(h3))};
  *(ushort4*)&xh[i] = hv;
  *(ushort4*)&xl[i] = lv;
}

// ---------------------------------------------------------------------------
// Split + transpose + COLUMN-PERMUTE Wqkv [256][6144] -> whT/wlT [6144][256].
// Original column n = seg*2048 + d*8 + h  ->  output row p = seg*2048 + h*256 + d.
// grid (96, 4), 256 thr.
// ---------------------------------------------------------------------------
__global__ __launch_bounds__(256) void conv_wT(const float* __restrict__ W,
                                               ushort* __restrict__ whT,
                                               ushort* __restrict__ wlT) {
  __shared__ float T[64][65];
  const int tid = threadIdx.x;
  const int n0 = blockIdx.x * 64;
  const int k0 = blockIdx.y * 64;
  {
    const int row = tid >> 2;
    const int c0 = (tid & 3) * 16;
#pragma unroll
    for (int j = 0; j < 16; j += 4) {
      const float4 v = *(const float4*)&W[(size_t)(k0 + row) * 6144 + n0 + c0 + j];
      T[row][c0 + j + 0] = v.x; T[row][c0 + j + 1] = v.y;
      T[row][c0 + j + 2] = v.z; T[row][c0 + j + 3] = v.w;
    }
  }
  __syncthreads();
  {
    const int nn = tid >> 2;
    const int kk0 = (tid & 3) * 16;
    const int n = n0 + nn;
    const int seg = n >> 11, h = n & 7, d = (n & 2047) >> 3;
    const int p = seg * 2048 + h * 256 + d;
    ushort hv[16], lv[16];
#pragma unroll
    for (int j = 0; j < 16; ++j) {
      const float v = T[kk0 + j][nn];
      hv[j] = f2bf(v);
      lv[j] = f2bf(v - bf2f(hv[j]));
    }
    const size_t base = (size_t)p * 256 + k0 + kk0;
#pragma unroll
    for (int j = 0; j < 16; j += 8) {
      *(v8s*)&whT[base + j] = *(v8s*)&hv[j];
      *(v8s*)&wlT[base + j] = *(v8s*)&lv[j];
    }
  }
}

// ---------------------------------------------------------------------------
// Transpose + k-PERMUTE W0 [2048][256] fp32 -> w0T [256][2048] bf16.
// w0T[e][h*256+d] = W0[d*8+h][e]  (matches vb's k layout).  grid (4, 32).
// ---------------------------------------------------------------------------
__global__ __launch_bounds__(256) void conv_w0T(const float* __restrict__ W0,
                                                ushort* __restrict__ w0T) {
  __shared__ float T[64][65];
  const int tid = threadIdx.x;
  const int e0 = blockIdx.x * 64;
  const int k0 = blockIdx.y * 64;
  {
    const int row = tid >> 2;          // k within tile
    const int c0 = (tid & 3) * 16;     // e within tile
#pragma unroll
    for (int j = 0; j < 16; j += 4) {
      const float4 v = *(const float4*)&W0[(size_t)(k0 + row) * 256 + e0 + c0 + j];
      T[row][c0 + j + 0] = v.x; T[row][c0 + j + 1] = v.y;
      T[row][c0 + j + 2] = v.z; T[row][c0 + j + 3] = v.w;
    }
  }
  __syncthreads();
  {
    const int ee = tid >> 2;
    const int kk0 = (tid & 3) * 16;
#pragma unroll
    for (int j = 0; j < 16; ++j) {
      const int k = k0 + kk0 + j;      // original row index = d*8+h
      const int d = k >> 3, h = k & 7;
      w0T[(size_t)(e0 + ee) * 2048 + h * 256 + d] = f2bf(T[kk0 + j][ee]);
    }
  }
}

// ---------------------------------------------------------------------------
// Kernel A: qkv = x @ Wqkv + bqkv via bf16x3 MFMA.  Permuted cols make the
// epilogue coalesced: all of q/k/v -> qkvb bf16 (q pre-scaled by 2^-4).
// grid (48, 32), 256 thr.
// ---------------------------------------------------------------------------
__global__ __launch_bounds__(256) void qkv_mfma(
    const ushort* __restrict__ xh, const ushort* __restrict__ xl,
    const ushort* __restrict__ whT, const ushort* __restrict__ wlT,
    const float* __restrict__ bias, ushort* __restrict__ qkvb) {
  __shared__ ushort As[128 * 32];
  __shared__ ushort Bs[128 * 32];
  const int tid = threadIdx.x;
  const int wave = tid >> 6, lane = tid & 63;
  const int quad = lane >> 4, l15 = lane & 15;
  const int c0 = blockIdx.x * 128;
  const int r0 = blockIdx.y * 128;
  const int wr = (wave >> 1) * 64;
  const int wc = (wave & 1) * 64;

  v4f acc[4][4] = {};

  for (int pass = 0; pass < 3; ++pass) {
    const ushort* Ap = (pass == 1) ? xl : xh;
    const ushort* Bp = (pass == 2) ? wlT : whT;
    for (int d0 = 0; d0 < 256; d0 += 32) {
#pragma unroll
      for (int half = 0; half < 2; ++half) {
        const int rr = wave * 32 + half * 16;
        const int row = rr + (lane >> 2);
        const int gcol = d0 + (lane & 3) * 8;
        GLOAD_LDS16(Ap + (size_t)(r0 + row) * 256 + gcol, &As[rr * 32]);
        GLOAD_LDS16(Bp + (size_t)(c0 + row) * 256 + gcol, &Bs[rr * 32]);
      }
      __syncthreads();

      v8s aF[4], bF[4];
#pragma unroll
      for (int i = 0; i < 4; ++i) {
        aF[i] = *(const v8s*)&As[(wr + i * 16 + l15) * 32 + quad * 8];
        bF[i] = *(const v8s*)&Bs[(wc + i * 16 + l15) * 32 + quad * 8];
      }
#pragma unroll
      for (int ri = 0; ri < 4; ++ri)
#pragma unroll
        for (int ci = 0; ci < 4; ++ci)
          acc[ri][ci] = __builtin_amdgcn_mfma_f32_16x16x32_bf16(
              aF[ri], bF[ci], acc[ri][ci], 0, 0, 0);
      __syncthreads();
    }
  }

  // Epilogue: C layout col=l15, row=quad*4+reg.  c' = seg*2048 + h*256 + d.
#pragma unroll
  for (int ci = 0; ci < 4; ++ci) {
    const int c = c0 + wc + ci * 16 + l15;
    const int cseg = c >> 11;
    const int h = (c & 2047) >> 8;
    const int d = c & 255;
    const float bv = bias[cseg * 2048 + d * 8 + h];
#pragma unroll
    for (int ri = 0; ri < 4; ++ri)
#pragma unroll
      for (int rg = 0; rg < 4; ++rg) {
        const int r = r0 + wr + ri * 16 + quad * 4 + rg;
        const int g = r * 3 + cseg;
        const int seg = g >> 12;       // q/k/v
        const int tok = g & 4095;
        float val = acc[ri][ci][rg] + bv;
        if (seg == 0) val *= 0.0625f;  // pre-scale q by D^-0.5
        qkvb[(size_t)seg * SEGSZ + (size_t)tok * 2048 + h * 256 + d] = f2bf(val);
      }
  }
}

// ---------------------------------------------------------------------------
// Kernel B: bf16 MFMA score stats over [tok][h*256+d] layout (stride 2048).
// grid (8 = t-tile, 8 = n-tile, 32 = b*h), 256 threads.
// ---------------------------------------------------------------------------
__global__ __launch_bounds__(256) void scores_mfma(
    const ushort* __restrict__ qkvb, float* __restrict__ pm,
    float* __restrict__ pl, float* __restrict__ sd_ws) {
  __shared__ ushort Qs[128 * 32];
  __shared__ ushort Ks[128 * 32];
  __shared__ float redM[2][2][64];
  __shared__ float redL[2][2][64];

  const int tid = threadIdx.x;
  const int wave = tid >> 6, lane = tid & 63;
  const int quad = lane >> 4, l15 = lane & 15;
  const int tt0 = blockIdx.x * 128;
  const int nn0 = blockIdx.y * 128;
  const int bh = blockIdx.z;
  const int b = bh >> 3, h = bh & 7;
  const ushort* Qg = qkvb + (size_t)b * 1024 * 2048 + h * 256;
  const ushort* Kg = Qg + SEGSZ;

  const int wr = (wave >> 1) * 64;
  const int wc = (wave & 1) * 64;

  v4f acc[4][4] = {};

  for (int d0 = 0; d0 < 256; d0 += 32) {
#pragma unroll
    for (int half = 0; half < 2; ++half) {
      const int rr = wave * 32 + half * 16;
      const int row = rr + (lane >> 2);
      const int gcol = d0 + (lane & 3) * 8;
      GLOAD_LDS16(Qg + (size_t)(nn0 + row) * 2048 + gcol, &Qs[rr * 32]);
      GLOAD_LDS16(Kg + (size_t)(tt0 + row) * 2048 + gcol, &Ks[rr * 32]);
    }
    __syncthreads();

    v8s aF[4], bF[4];
#pragma unroll
    for (int i = 0; i < 4; ++i) {
      aF[i] = *(const v8s*)&Qs[(wr + i * 16 + l15) * 32 + quad * 8];
      bF[i] = *(const v8s*)&Ks[(wc + i * 16 + l15) * 32 + quad * 8];
    }
#pragma unroll
    for (int ri = 0; ri < 4; ++ri)
#pragma unroll
      for (int ci = 0; ci < 4; ++ci)
        acc[ri][ci] =
            __builtin_amdgcn_mfma_f32_16x16x32_bf16(aF[ri], bF[ci], acc[ri][ci], 0, 0, 0);
    __syncthreads();
  }

  float mloc[4];
#pragma unroll
  for (int ci = 0; ci < 4; ++ci) {
    float m = acc[0][ci][0];
#pragma unroll
    for (int ri = 0; ri < 4; ++ri)
#pragma unroll
      for (int rg = 0; rg < 4; ++rg) m = fmaxf(m, acc[ri][ci][rg]);
    m = fmaxf(m, __shfl_xor(m, 16, 64));
    m = fmaxf(m, __shfl_xor(m, 32, 64));
    mloc[ci] = m;
  }
  if (quad == 0) {
#pragma unroll
    for (int ci = 0; ci < 4; ++ci)
      redM[wave & 1][wave >> 1][ci * 16 + l15] = mloc[ci];
  }
  __syncthreads();
  float mfull[4], lsum[4];
#pragma unroll
  for (int ci = 0; ci < 4; ++ci) {
    const float m = fmaxf(mloc[ci], redM[wave & 1][1 - (wave >> 1)][ci * 16 + l15]);
    mfull[ci] = m;
    float s = 0.f;
#pragma unroll
    for (int ri = 0; ri < 4; ++ri)
#pragma unroll
      for (int rg = 0; rg < 4; ++rg) s += __expf(acc[ri][ci][rg] - m);
    s += __shfl_xor(s, 16, 64);
    s += __shfl_xor(s, 32, 64);
    lsum[ci] = s;
  }
  if (quad == 0) {
#pragma unroll
    for (int ci = 0; ci < 4; ++ci)
      redL[wave & 1][wave >> 1][ci * 16 + l15] = lsum[ci];
  }
  __syncthreads();
  if ((wave >> 1) == 0 && quad == 0) {
#pragma unroll
    for (int ci = 0; ci < 4; ++ci) {
      const int t = tt0 + (wave & 1) * 64 + ci * 16 + l15;
      const float l = lsum[ci] + redL[wave & 1][1][ci * 16 + l15];
      const size_t idx = ((size_t)bh * 1024 + t) * 8 + blockIdx.y;
      pm[idx] = mfull[ci];
      pl[idx] = l;
    }
  }

  if (tt0 == nn0 && (wave == 0 || wave == 3) && quad == (l15 >> 2)) {
#pragma unroll
    for (int ri = 0; ri < 4; ++ri) {
      const int t = tt0 + (wave & 1) * 64 + ri * 16 + l15;
      sd_ws[(size_t)bh * 1024 + t] = acc[ri][ri][l15 & 3];
    }
  }
}

// ---------------------------------------------------------------------------
// Merge partial stats (8 chunks) -> diag[tok][h].  grid (128), 256 thr.
// ---------------------------------------------------------------------------
__global__ void merge_diag(const float* __restrict__ pm, const float* __restrict__ pl,
                           const float* __restrict__ sd, float* __restrict__ diag) {
  const int i = blockIdx.x * 256 + threadIdx.x;  // (b*8+h)*1024 + t
  float m = -1e30f;
#pragma unroll
  for (int c = 0; c < 8; ++c) m = fmaxf(m, pm[(size_t)i * 8 + c]);
  float l = 0.f;
#pragma unroll
  for (int c = 0; c < 8; ++c)
    l += pl[(size_t)i * 8 + c] * __expf(pm[(size_t)i * 8 + c] - m);
  const float dg = __expf(sd[i] - m) / l;
  const int t = i & 1023;
  const int bh = i >> 10;
  const int b = bh >> 3, h = bh & 7;
  diag[(((size_t)(b * 1024 + t)) << 3) + h] = dg;
}

// ---------------------------------------------------------------------------
// Scale v in-place by diag: vb[tok][k] *= diag[tok][k>>8].  grid (4096), 256 thr.
// ---------------------------------------------------------------------------
__global__ void scale_v(ushort* __restrict__ vb, const float* __restrict__ diag) {
  const size_t gid = (size_t)blockIdx.x * 256 + threadIdx.x;
  const size_t flat = gid * 8;
  const int tok = (int)(flat >> 11);
  const int h = (int)((flat & 2047) >> 8);
  const float dg = diag[(size_t)tok * 8 + h];
  v8s v = *(v8s*)&vb[flat];
  ushort o[8];
#pragma unroll
  for (int j = 0; j < 8; ++j) o[j] = f2bf(bf2f((ushort)v[j]) * dg);
  *(v8s*)&vb[flat] = *(v8s*)o;
}

// ---------------------------------------------------------------------------
// Kernel C: out = (diag*v) @ W0  via bf16 MFMA, split-K=4 over k=2048.
// grid (2 = e-tile, 32 = tok-tile, 4 = kc), 256 thr, 128x128 tile.
// ---------------------------------------------------------------------------
template <bool ATOMIC>
__global__ __launch_bounds__(256) void av_mfma(
    const ushort* __restrict__ vb, const ushort* __restrict__ w0T,
    float* __restrict__ partial, float* __restrict__ out) {
  __shared__ ushort As[128 * 32];
  __shared__ ushort Bs[128 * 32];
  const int tid = threadIdx.x;
  const int wave = tid >> 6, lane = tid & 63;
  const int quad = lane >> 4, l15 = lane & 15;
  const int e0 = blockIdx.x * 128;
  const int tok0 = blockIdx.y * 128;
  const int kbase = blockIdx.z * 512;
  const int wr = (wave >> 1) * 64;
  const int wc = (wave & 1) * 64;

  v4f acc[4][4] = {};

  for (int d0 = 0; d0 < 512; d0 += 32) {
#pragma unroll
    for (int half = 0; half < 2; ++half) {
      const int rr = wave * 32 + half * 16;
      const int row = rr + (lane >> 2);
      const int gcol = kbase + d0 + (lane & 3) * 8;
      GLOAD_LDS16(vb + (size_t)(tok0 + row) * 2048 + gcol, &As[rr * 32]);
      GLOAD_LDS16(w0T + (size_t)(e0 + row) * 2048 + gcol, &Bs[rr * 32]);
    }
    __syncthreads();

    v8s aF[4], bF[4];
#pragma unroll
    for (int i = 0; i < 4; ++i) {
      aF[i] = *(const v8s*)&As[(wr + i * 16 + l15) * 32 + quad * 8];
      bF[i] = *(const v8s*)&Bs[(wc + i * 16 + l15) * 32 + quad * 8];
    }
#pragma unroll
    for (int ri = 0; ri < 4; ++ri)
#pragma unroll
      for (int ci = 0; ci < 4; ++ci)
        acc[ri][ci] =
            __builtin_amdgcn_mfma_f32_16x16x32_bf16(aF[ri], bF[ci], acc[ri][ci], 0, 0, 0);
    __syncthreads();
  }

#pragma unroll
  for (int ci = 0; ci < 4; ++ci) {
    const int e = e0 + wc + ci * 16 + l15;
#pragma unroll
    for (int ri = 0; ri < 4; ++ri)
#pragma unroll
      for (int rg = 0; rg < 4; ++rg) {
        const int tok = tok0 + wr + ri * 16 + quad * 4 + rg;
        if (ATOMIC)
          atomicAdd(&out[(size_t)tok * 256 + e], acc[ri][ci][rg]);
        else
          partial[(size_t)blockIdx.z * 1048576 + (size_t)tok * 256 + e] =
              acc[ri][ci][rg];
      }
  }
}

__global__ void init_out(const float* __restrict__ b0, float* __restrict__ out) {
  const int i = blockIdx.x * 256 + threadIdx.x;
  const int e0 = (i & 63) << 2;
  *(float4*)&out[(size_t)i * 4] = *(const float4*)&b0[e0];
}

__global__ void reduce_out(const float* __restrict__ partial, const float* __restrict__ b0,
                           float* __restrict__ out) {
  const int i = blockIdx.x * 256 + threadIdx.x;  // 262144 float4 groups
  const int e0 = (i & 63) << 2;
  float4 a = *(const float4*)&b0[e0];
#pragma unroll
  for (int kc = 0; kc < 4; ++kc) {
    const float4 p = *(const float4*)&partial[(size_t)kc * 1048576 + (size_t)i * 4];
    a.x += p.x; a.y += p.y; a.z += p.z; a.w += p.w;
  }
  *(float4*)&out[(size_t)i * 4] = a;
}

extern "C" void kernel_launch(void* const* d_in, const int* in_sizes, int n_in,
                              void* d_out, int out_size, void* d_ws, size_t ws_size,
                              hipStream_t stream) {
  const float* x    = (const float*)d_in[0];
  const float* Wqkv = (const float*)d_in[1];
  const float* bqkv = (const float*)d_in[2];
  const float* W0   = (const float*)d_in[3];
  const float* b0   = (const float*)d_in[4];
  float* out = (float*)d_out;

  float*  pm   = (float*)d_ws;                     // 262144 f
  float*  pl   = pm + 262144;                      // 262144 f
  float*  sd   = pl + 262144;                      // 32768 f
  float*  diag = sd + 32768;                       // 32768 f
  ushort* qkvb = (ushort*)(diag + 32768);          // 3*SEGSZ us (q|k|v)
  ushort* xh   = qkvb + 3 * (size_t)SEGSZ;         // 1048576 us
  ushort* xl   = xh + 1048576;                     // 1048576 us
  ushort* whT  = xl + 1048576;                     // 1572864 us
  ushort* wlT  = whT + 1572864;                    // 1572864 us
  ushort* w0T  = wlT + 1572864;                    // 524288 us
  float*  partial = (float*)(w0T + 524288);        // 4*1048576 f (optional)

  ushort* vb = qkvb + 2 * (size_t)SEGSZ;

  const size_t need_base =
      (size_t)(262144 * 2 + 32768 * 2) * 4 + (size_t)SEGSZ * 3 * 2 +
      (size_t)(1048576 * 2 + 1572864 * 2 + 524288) * 2;
  const bool full = ws_size >= need_base + (size_t)4 * 1048576 * 4;

  conv_x<<<1024, 256, 0, stream>>>(x, xh, xl);
  conv_wT<<<dim3(96, 4), 256, 0, stream>>>(Wqkv, whT, wlT);
  conv_w0T<<<dim3(4, 32), 256, 0, stream>>>(W0, w0T);
  qkv_mfma<<<dim3(48, 32), 256, 0, stream>>>(xh, xl, whT, wlT, bqkv, qkvb);
  scores_mfma<<<dim3(8, 8, 32), 256, 0, stream>>>(qkvb, pm, pl, sd);
  merge_diag<<<128, 256, 0, stream>>>(pm, pl, sd, diag);
  scale_v<<<4096, 256, 0, stream>>>(vb, diag);
  if (full) {
    av_mfma<false><<<dim3(2, 32, 4), 256, 0, stream>>>(vb, w0T, partial, out);
    reduce_out<<<1024, 256, 0, stream>>>(partial, b0, out);
  } else {
    init_out<<<1024, 256, 0, stream>>>(b0, out);
    av_mfma<true><<<dim3(2, 32, 4), 256, 0, stream>>>(vb, w0T, nullptr, out);
  }
}

// Round 6
// 164.385 us; speedup vs baseline: 3.1844x; 1.1029x over previous
//
#include <hip/hip_runtime.h>

// Problem constants: B=4, N=1024, D=256, H=8
// q/k/v stored bf16 in qkvb[seg][tok][h*256+d]  (tok-major, stride 2048),
// tok = b*1024+n.  Wqkv pre-transposed + column-permuted: whT/wlT row
// p = seg*2048+h*256+d holds original column seg*2048+d*8+h (coalesced
// qkv epilogue).  W0 pre-transposed with the same k-permutation:
// w0T[e][h*256+d] = W0[d*8+h][e].
// qkv GEMM is bf16x2: xb @ (wh + wl), fp32 MFMA accumulation.
// av GEMM splits K by h so diag[tok][h] is applied per-chunk in the epilogue.

#define SEGSZ 8388608  // elements per q/k/v segment = 4096 tok * 2048

typedef short v8s __attribute__((ext_vector_type(8)));
typedef float v4f __attribute__((ext_vector_type(4)));

__device__ __forceinline__ ushort f2bf(float v) {
  union { float f; unsigned u; } x; x.f = v;
  const unsigned r = x.u + 0x7fff + ((x.u >> 16) & 1);   // RTNE
  return (ushort)(r >> 16);
}
__device__ __forceinline__ float bf2f(ushort v) {
  union { unsigned u; float f; } x; x.u = ((unsigned)v) << 16;
  return x.f;
}

#define GLOAD_LDS16(g, l)                                            \
  __builtin_amdgcn_global_load_lds(                                  \
      (const __attribute__((address_space(1))) void*)(g),            \
      (__attribute__((address_space(3))) void*)(l), 16, 0, 0)

// ---------------------------------------------------------------------------
// Round x (fp32) to bf16.  grid (1024), 256 thr, 4 elems/thr.
// ---------------------------------------------------------------------------
__global__ void conv_x(const float* __restrict__ X, ushort* __restrict__ xb) {
  const size_t i = ((size_t)blockIdx.x * 256 + threadIdx.x) * 4;
  const float4 v = *(const float4*)&X[i];
  ushort4 hv = {f2bf(v.x), f2bf(v.y), f2bf(v.z), f2bf(v.w)};
  *(ushort4*)&xb[i] = hv;
}

// ---------------------------------------------------------------------------
// Split + transpose + COLUMN-PERMUTE Wqkv [256][6144] -> whT/wlT [6144][256].
// Original column n = seg*2048 + d*8 + h  ->  output row p = seg*2048 + h*256 + d.
// grid (96, 4), 256 thr.
// ---------------------------------------------------------------------------
__global__ __launch_bounds__(256) void conv_wT(const float* __restrict__ W,
                                               ushort* __restrict__ whT,
                                               ushort* __restrict__ wlT) {
  __shared__ float T[64][65];
  const int tid = threadIdx.x;
  const int n0 = blockIdx.x * 64;
  const int k0 = blockIdx.y * 64;
  {
    const int row = tid >> 2;
    const int c0 = (tid & 3) * 16;
#pragma unroll
    for (int j = 0; j < 16; j += 4) {
      const float4 v = *(const float4*)&W[(size_t)(k0 + row) * 6144 + n0 + c0 + j];
      T[row][c0 + j + 0] = v.x; T[row][c0 + j + 1] = v.y;
      T[row][c0 + j + 2] = v.z; T[row][c0 + j + 3] = v.w;
    }
  }
  __syncthreads();
  {
    const int nn = tid >> 2;
    const int kk0 = (tid & 3) * 16;
    const int n = n0 + nn;
    const int seg = n >> 11, h = n & 7, d = (n & 2047) >> 3;
    const int p = seg * 2048 + h * 256 + d;
    ushort hv[16], lv[16];
#pragma unroll
    for (int j = 0; j < 16; ++j) {
      const float v = T[kk0 + j][nn];
      hv[j] = f2bf(v);
      lv[j] = f2bf(v - bf2f(hv[j]));
    }
    const size_t base = (size_t)p * 256 + k0 + kk0;
#pragma unroll
    for (int j = 0; j < 16; j += 8) {
      *(v8s*)&whT[base + j] = *(v8s*)&hv[j];
      *(v8s*)&wlT[base + j] = *(v8s*)&lv[j];
    }
  }
}

// ---------------------------------------------------------------------------
// Transpose + k-PERMUTE W0 [2048][256] fp32 -> w0T [256][2048] bf16.
// w0T[e][h*256+d] = W0[d*8+h][e].  grid (4, 32).
// ---------------------------------------------------------------------------
__global__ __launch_bounds__(256) void conv_w0T(const float* __restrict__ W0,
                                                ushort* __restrict__ w0T) {
  __shared__ float T[64][65];
  const int tid = threadIdx.x;
  const int e0 = blockIdx.x * 64;
  const int k0 = blockIdx.y * 64;
  {
    const int row = tid >> 2;          // k within tile
    const int c0 = (tid & 3) * 16;     // e within tile
#pragma unroll
    for (int j = 0; j < 16; j += 4) {
      const float4 v = *(const float4*)&W0[(size_t)(k0 + row) * 256 + e0 + c0 + j];
      T[row][c0 + j + 0] = v.x; T[row][c0 + j + 1] = v.y;
      T[row][c0 + j + 2] = v.z; T[row][c0 + j + 3] = v.w;
    }
  }
  __syncthreads();
  {
    const int ee = tid >> 2;
    const int kk0 = (tid & 3) * 16;
#pragma unroll
    for (int j = 0; j < 16; ++j) {
      const int k = k0 + kk0 + j;      // original row index = d*8+h
      const int d = k >> 3, h = k & 7;
      w0T[(size_t)(e0 + ee) * 2048 + h * 256 + d] = f2bf(T[kk0 + j][ee]);
    }
  }
}

// ---------------------------------------------------------------------------
// Kernel A: qkv = x @ Wqkv + bqkv via bf16x2 MFMA: xb @ (wh + wl), A-tile
// staged once per k-chunk.  grid (48, 32), 256 thr, 128x128 tile.
// ---------------------------------------------------------------------------
__global__ __launch_bounds__(256) void qkv_mfma(
    const ushort* __restrict__ xb, const ushort* __restrict__ whT,
    const ushort* __restrict__ wlT, const float* __restrict__ bias,
    ushort* __restrict__ qkvb) {
  __shared__ ushort As[128 * 32];
  __shared__ ushort Bh[128 * 32];
  __shared__ ushort Bl[128 * 32];
  const int tid = threadIdx.x;
  const int wave = tid >> 6, lane = tid & 63;
  const int quad = lane >> 4, l15 = lane & 15;
  const int c0 = blockIdx.x * 128;
  const int r0 = blockIdx.y * 128;
  const int wr = (wave >> 1) * 64;
  const int wc = (wave & 1) * 64;

  v4f acc[4][4] = {};

  for (int d0 = 0; d0 < 256; d0 += 32) {
#pragma unroll
    for (int half = 0; half < 2; ++half) {
      const int rr = wave * 32 + half * 16;
      const int row = rr + (lane >> 2);
      const int gcol = d0 + (lane & 3) * 8;
      GLOAD_LDS16(xb + (size_t)(r0 + row) * 256 + gcol, &As[rr * 32]);
      GLOAD_LDS16(whT + (size_t)(c0 + row) * 256 + gcol, &Bh[rr * 32]);
      GLOAD_LDS16(wlT + (size_t)(c0 + row) * 256 + gcol, &Bl[rr * 32]);
    }
    __syncthreads();

    v8s aF[4], bh_[4], bl_[4];
#pragma unroll
    for (int i = 0; i < 4; ++i) {
      aF[i]  = *(const v8s*)&As[(wr + i * 16 + l15) * 32 + quad * 8];
      bh_[i] = *(const v8s*)&Bh[(wc + i * 16 + l15) * 32 + quad * 8];
      bl_[i] = *(const v8s*)&Bl[(wc + i * 16 + l15) * 32 + quad * 8];
    }
#pragma unroll
    for (int ri = 0; ri < 4; ++ri)
#pragma unroll
      for (int ci = 0; ci < 4; ++ci) {
        acc[ri][ci] = __builtin_amdgcn_mfma_f32_16x16x32_bf16(
            aF[ri], bh_[ci], acc[ri][ci], 0, 0, 0);
        acc[ri][ci] = __builtin_amdgcn_mfma_f32_16x16x32_bf16(
            aF[ri], bl_[ci], acc[ri][ci], 0, 0, 0);
      }
    __syncthreads();
  }

  // Epilogue: C layout col=l15, row=quad*4+reg.  c' = seg*2048 + h*256 + d.
#pragma unroll
  for (int ci = 0; ci < 4; ++ci) {
    const int c = c0 + wc + ci * 16 + l15;
    const int cseg = c >> 11;
    const int h = (c & 2047) >> 8;
    const int d = c & 255;
    const float bv = bias[cseg * 2048 + d * 8 + h];
#pragma unroll
    for (int ri = 0; ri < 4; ++ri)
#pragma unroll
      for (int rg = 0; rg < 4; ++rg) {
        const int r = r0 + wr + ri * 16 + quad * 4 + rg;
        const int g = r * 3 + cseg;
        const int seg = g >> 12;       // q/k/v
        const int tok = g & 4095;      // = b*1024 + n
        float val = acc[ri][ci][rg] + bv;
        if (seg == 0) val *= 0.0625f;  // pre-scale q by D^-0.5
        qkvb[(size_t)seg * SEGSZ + (size_t)tok * 2048 + h * 256 + d] = f2bf(val);
      }
  }
}

// ---------------------------------------------------------------------------
// Kernel B: bf16 MFMA score stats over [tok][h*256+d] layout (stride 2048).
// grid (8 = t-tile, 8 = n-tile, 32 = b*h), 256 threads.
// ---------------------------------------------------------------------------
__global__ __launch_bounds__(256) void scores_mfma(
    const ushort* __restrict__ qkvb, float* __restrict__ pm,
    float* __restrict__ pl, float* __restrict__ sd_ws) {
  __shared__ ushort Qs[128 * 32];
  __shared__ ushort Ks[128 * 32];
  __shared__ float redM[2][2][64];
  __shared__ float redL[2][2][64];

  const int tid = threadIdx.x;
  const int wave = tid >> 6, lane = tid & 63;
  const int quad = lane >> 4, l15 = lane & 15;
  const int tt0 = blockIdx.x * 128;
  const int nn0 = blockIdx.y * 128;
  const int bh = blockIdx.z;
  const int b = bh >> 3, h = bh & 7;
  const ushort* Qg = qkvb + (size_t)b * 1024 * 2048 + h * 256;
  const ushort* Kg = Qg + SEGSZ;

  const int wr = (wave >> 1) * 64;
  const int wc = (wave & 1) * 64;

  v4f acc[4][4] = {};

  for (int d0 = 0; d0 < 256; d0 += 32) {
#pragma unroll
    for (int half = 0; half < 2; ++half) {
      const int rr = wave * 32 + half * 16;
      const int row = rr + (lane >> 2);
      const int gcol = d0 + (lane & 3) * 8;
      GLOAD_LDS16(Qg + (size_t)(nn0 + row) * 2048 + gcol, &Qs[rr * 32]);
      GLOAD_LDS16(Kg + (size_t)(tt0 + row) * 2048 + gcol, &Ks[rr * 32]);
    }
    __syncthreads();

    v8s aF[4], bF[4];
#pragma unroll
    for (int i = 0; i < 4; ++i) {
      aF[i] = *(const v8s*)&Qs[(wr + i * 16 + l15) * 32 + quad * 8];
      bF[i] = *(const v8s*)&Ks[(wc + i * 16 + l15) * 32 + quad * 8];
    }
#pragma unroll
    for (int ri = 0; ri < 4; ++ri)
#pragma unroll
      for (int ci = 0; ci < 4; ++ci)
        acc[ri][ci] =
            __builtin_amdgcn_mfma_f32_16x16x32_bf16(aF[ri], bF[ci], acc[ri][ci], 0, 0, 0);
    __syncthreads();
  }

  float mloc[4];
#pragma unroll
  for (int ci = 0; ci < 4; ++ci) {
    float m = acc[0][ci][0];
#pragma unroll
    for (int ri = 0; ri < 4; ++ri)
#pragma unroll
      for (int rg = 0; rg < 4; ++rg) m = fmaxf(m, acc[ri][ci][rg]);
    m = fmaxf(m, __shfl_xor(m, 16, 64));
    m = fmaxf(m, __shfl_xor(m, 32, 64));
    mloc[ci] = m;
  }
  if (quad == 0) {
#pragma unroll
    for (int ci = 0; ci < 4; ++ci)
      redM[wave & 1][wave >> 1][ci * 16 + l15] = mloc[ci];
  }
  __syncthreads();
  float mfull[4], lsum[4];
#pragma unroll
  for (int ci = 0; ci < 4; ++ci) {
    const float m = fmaxf(mloc[ci], redM[wave & 1][1 - (wave >> 1)][ci * 16 + l15]);
    mfull[ci] = m;
    float s = 0.f;
#pragma unroll
    for (int ri = 0; ri < 4; ++ri)
#pragma unroll
      for (int rg = 0; rg < 4; ++rg) s += __expf(acc[ri][ci][rg] - m);
    s += __shfl_xor(s, 16, 64);
    s += __shfl_xor(s, 32, 64);
    lsum[ci] = s;
  }
  if (quad == 0) {
#pragma unroll
    for (int ci = 0; ci < 4; ++ci)
      redL[wave & 1][wave >> 1][ci * 16 + l15] = lsum[ci];
  }
  __syncthreads();
  if ((wave >> 1) == 0 && quad == 0) {
#pragma unroll
    for (int ci = 0; ci < 4; ++ci) {
      const int t = tt0 + (wave & 1) * 64 + ci * 16 + l15;
      const float l = lsum[ci] + redL[wave & 1][1][ci * 16 + l15];
      const size_t idx = ((size_t)bh * 1024 + t) * 8 + blockIdx.y;
      pm[idx] = mfull[ci];
      pl[idx] = l;
    }
  }

  if (tt0 == nn0 && (wave == 0 || wave == 3) && quad == (l15 >> 2)) {
#pragma unroll
    for (int ri = 0; ri < 4; ++ri) {
      const int t = tt0 + (wave & 1) * 64 + ri * 16 + l15;
      sd_ws[(size_t)bh * 1024 + t] = acc[ri][ri][l15 & 3];
    }
  }
}

// ---------------------------------------------------------------------------
// Merge partial stats (8 chunks) -> diag[tok][h].  grid (128), 256 thr.
// ---------------------------------------------------------------------------
__global__ void merge_diag(const float* __restrict__ pm, const float* __restrict__ pl,
                           const float* __restrict__ sd, float* __restrict__ diag) {
  const int i = blockIdx.x * 256 + threadIdx.x;  // (b*8+h)*1024 + t
  float m = -1e30f;
#pragma unroll
  for (int c = 0; c < 8; ++c) m = fmaxf(m, pm[(size_t)i * 8 + c]);
  float l = 0.f;
#pragma unroll
  for (int c = 0; c < 8; ++c)
    l += pl[(size_t)i * 8 + c] * __expf(pm[(size_t)i * 8 + c] - m);
  const float dg = __expf(sd[i] - m) / l;
  const int t = i & 1023;
  const int bh = i >> 10;
  const int b = bh >> 3, h = bh & 7;
  diag[(((size_t)(b * 1024 + t)) << 3) + h] = dg;
}

// ---------------------------------------------------------------------------
// Kernel C: out = (diag.v) @ W0 via bf16 MFMA, split-K BY HEAD (8 chunks of
// 256): within a chunk diag[tok][h] is row-constant -> applied in epilogue.
// grid (2 = e-tile, 32 = tok-tile, 8 = h), 256 thr, 128x128 tile.
// ---------------------------------------------------------------------------
template <bool ATOMIC>
__global__ __launch_bounds__(256) void av_mfma(
    const ushort* __restrict__ vb, const ushort* __restrict__ w0T,
    const float* __restrict__ diag, float* __restrict__ partial,
    float* __restrict__ out) {
  __shared__ ushort As[128 * 32];
  __shared__ ushort Bs[128 * 32];
  const int tid = threadIdx.x;
  const int wave = tid >> 6, lane = tid & 63;
  const int quad = lane >> 4, l15 = lane & 15;
  const int e0 = blockIdx.x * 128;
  const int tok0 = blockIdx.y * 128;
  const int h = blockIdx.z;
  const int kbase = h * 256;
  const int wr = (wave >> 1) * 64;
  const int wc = (wave & 1) * 64;

  v4f acc[4][4] = {};

  for (int d0 = 0; d0 < 256; d0 += 32) {
#pragma unroll
    for (int half = 0; half < 2; ++half) {
      const int rr = wave * 32 + half * 16;
      const int row = rr + (lane >> 2);
      const int gcol = kbase + d0 + (lane & 3) * 8;
      GLOAD_LDS16(vb + (size_t)(tok0 + row) * 2048 + gcol, &As[rr * 32]);
      GLOAD_LDS16(w0T + (size_t)(e0 + row) * 2048 + gcol, &Bs[rr * 32]);
    }
    __syncthreads();

    v8s aF[4], bF[4];
#pragma unroll
    for (int i = 0; i < 4; ++i) {
      aF[i] = *(const v8s*)&As[(wr + i * 16 + l15) * 32 + quad * 8];
      bF[i] = *(const v8s*)&Bs[(wc + i * 16 + l15) * 32 + quad * 8];
    }
#pragma unroll
    for (int ri = 0; ri < 4; ++ri)
#pragma unroll
      for (int ci = 0; ci < 4; ++ci)
        acc[ri][ci] =
            __builtin_amdgcn_mfma_f32_16x16x32_bf16(aF[ri], bF[ci], acc[ri][ci], 0, 0, 0);
    __syncthreads();
  }

#pragma unroll
  for (int ri = 0; ri < 4; ++ri)
#pragma unroll
    for (int rg = 0; rg < 4; ++rg) {
      const int tok = tok0 + wr + ri * 16 + quad * 4 + rg;
      const float dg = diag[(size_t)tok * 8 + h];
#pragma unroll
      for (int ci = 0; ci < 4; ++ci) {
        const int e = e0 + wc + ci * 16 + l15;
        const float val = acc[ri][ci][rg] * dg;
        if (ATOMIC)
          atomicAdd(&out[(size_t)tok * 256 + e], val);
        else
          partial[(size_t)h * 1048576 + (size_t)tok * 256 + e] = val;
      }
    }
}

__global__ void init_out(const float* __restrict__ b0, float* __restrict__ out) {
  const int i = blockIdx.x * 256 + threadIdx.x;
  const int e0 = (i & 63) << 2;
  *(float4*)&out[(size_t)i * 4] = *(const float4*)&b0[e0];
}

__global__ void reduce_out(const float* __restrict__ partial, const float* __restrict__ b0,
                           float* __restrict__ out) {
  const int i = blockIdx.x * 256 + threadIdx.x;  // 262144 float4 groups
  const int e0 = (i & 63) << 2;
  float4 a = *(const float4*)&b0[e0];
#pragma unroll
  for (int h = 0; h < 8; ++h) {
    const float4 p = *(const float4*)&partial[(size_t)h * 1048576 + (size_t)i * 4];
    a.x += p.x; a.y += p.y; a.z += p.z; a.w += p.w;
  }
  *(float4*)&out[(size_t)i * 4] = a;
}

extern "C" void kernel_launch(void* const* d_in, const int* in_sizes, int n_in,
                              void* d_out, int out_size, void* d_ws, size_t ws_size,
                              hipStream_t stream) {
  const float* x    = (const float*)d_in[0];
  const float* Wqkv = (const float*)d_in[1];
  const float* bqkv = (const float*)d_in[2];
  const float* W0   = (const float*)d_in[3];
  const float* b0   = (const float*)d_in[4];
  float* out = (float*)d_out;

  float*  pm   = (float*)d_ws;                     // 262144 f
  float*  pl   = pm + 262144;                      // 262144 f
  float*  sd   = pl + 262144;                      // 32768 f
  float*  diag = sd + 32768;                       // 32768 f
  ushort* qkvb = (ushort*)(diag + 32768);          // 3*SEGSZ us (q|k|v)
  ushort* xb   = qkvb + 3 * (size_t)SEGSZ;         // 1048576 us
  ushort* whT  = xb + 1048576;                     // 1572864 us
  ushort* wlT  = whT + 1572864;                    // 1572864 us
  ushort* w0T  = wlT + 1572864;                    // 524288 us
  float*  partial = (float*)(w0T + 524288);        // 8*1048576 f (optional)

  ushort* vb = qkvb + 2 * (size_t)SEGSZ;

  const size_t need_base =
      (size_t)(262144 * 2 + 32768 * 2) * 4 + (size_t)SEGSZ * 3 * 2 +
      (size_t)(1048576 + 1572864 * 2 + 524288) * 2;
  const bool full = ws_size >= need_base + (size_t)8 * 1048576 * 4;

  conv_x<<<1024, 256, 0, stream>>>(x, xb);
  conv_wT<<<dim3(96, 4), 256, 0, stream>>>(Wqkv, whT, wlT);
  conv_w0T<<<dim3(4, 32), 256, 0, stream>>>(W0, w0T);
  qkv_mfma<<<dim3(48, 32), 256, 0, stream>>>(xb, whT, wlT, bqkv, qkvb);
  scores_mfma<<<dim3(8, 8, 32), 256, 0, stream>>>(qkvb, pm, pl, sd);
  merge_diag<<<128, 256, 0, stream>>>(pm, pl, sd, diag);
  if (full) {
    av_mfma<false><<<dim3(2, 32, 8), 256, 0, stream>>>(vb, w0T, diag, partial, out);
    reduce_out<<<1024, 256, 0, stream>>>(partial, b0, out);
  } else {
    init_out<<<1024, 256, 0, stream>>>(b0, out);
    av_mfma<true><<<dim3(2, 32, 8), 256, 0, stream>>>(vb, w0T, diag, nullptr, out);
  }
}

// Round 7
// 153.572 us; speedup vs baseline: 3.4086x; 1.0704x over previous
//
#include <hip/hip_runtime.h>

// Problem constants: B=4, N=1024, D=256, H=8
// q/k/v stored bf16 in qkvb[seg][tok][h*256+d]  (tok-major, stride 2048),
// tok = b*1024+n.  Wqkv pre-transposed + column-permuted: whT/wlT row
// p = seg*2048+h*256+d holds original column seg*2048+d*8+h (coalesced
// qkv epilogue).  W0 pre-transposed with the same k-permutation:
// w0T[e][h*256+d] = W0[d*8+h][e].
// qkv GEMM: bf16x2 (xb @ (wh+wl)) for q,k; bf16x1 (xb @ wh) for v blocks.
// av GEMM splits K by head; diag computed in-kernel from pm/pl/sd; bf16 partials.

#define SEGSZ 8388608  // elements per q/k/v segment = 4096 tok * 2048

typedef short v8s __attribute__((ext_vector_type(8)));
typedef float v4f __attribute__((ext_vector_type(4)));

__device__ __forceinline__ ushort f2bf(float v) {
  union { float f; unsigned u; } x; x.f = v;
  const unsigned r = x.u + 0x7fff + ((x.u >> 16) & 1);   // RTNE
  return (ushort)(r >> 16);
}
__device__ __forceinline__ float bf2f(ushort v) {
  union { unsigned u; float f; } x; x.u = ((unsigned)v) << 16;
  return x.f;
}

#define GLOAD_LDS16(g, l)                                            \
  __builtin_amdgcn_global_load_lds(                                  \
      (const __attribute__((address_space(1))) void*)(g),            \
      (__attribute__((address_space(3))) void*)(l), 16, 0, 0)

// ---------------------------------------------------------------------------
// prep: fused conversions.  blocks 0..1023: x->xb (bf16).
// blocks 1024..1407: Wqkv split+transpose+permute -> whT/wlT.
// blocks 1408..1535: W0 transpose+permute -> w0T.  grid (1536), 256 thr.
// ---------------------------------------------------------------------------
__global__ __launch_bounds__(256) void prep(
    const float* __restrict__ X, const float* __restrict__ Wqkv,
    const float* __restrict__ W0, ushort* __restrict__ xb,
    ushort* __restrict__ whT, ushort* __restrict__ wlT,
    ushort* __restrict__ w0T) {
  __shared__ float T[64][65];
  const int tid = threadIdx.x;
  int bid = blockIdx.x;

  if (bid < 1024) {  // ---- x -> bf16 ----
    const size_t i = ((size_t)bid * 256 + tid) * 4;
    const float4 v = *(const float4*)&X[i];
    ushort4 hv = {f2bf(v.x), f2bf(v.y), f2bf(v.z), f2bf(v.w)};
    *(ushort4*)&xb[i] = hv;
    return;
  }
  bid -= 1024;
  if (bid < 384) {  // ---- Wqkv [256][6144] -> whT/wlT [6144][256], permuted ----
    const int n0 = (bid % 96) * 64;
    const int k0 = (bid / 96) * 64;
    {
      const int row = tid >> 2;
      const int c0 = (tid & 3) * 16;
#pragma unroll
      for (int j = 0; j < 16; j += 4) {
        const float4 v = *(const float4*)&Wqkv[(size_t)(k0 + row) * 6144 + n0 + c0 + j];
        T[row][c0 + j + 0] = v.x; T[row][c0 + j + 1] = v.y;
        T[row][c0 + j + 2] = v.z; T[row][c0 + j + 3] = v.w;
      }
    }
    __syncthreads();
    {
      const int nn = tid >> 2;
      const int kk0 = (tid & 3) * 16;
      const int n = n0 + nn;
      const int seg = n >> 11, h = n & 7, d = (n & 2047) >> 3;
      const int p = seg * 2048 + h * 256 + d;
      ushort hv[16], lv[16];
#pragma unroll
      for (int j = 0; j < 16; ++j) {
        const float v = T[kk0 + j][nn];
        hv[j] = f2bf(v);
        lv[j] = f2bf(v - bf2f(hv[j]));
      }
      const size_t base = (size_t)p * 256 + k0 + kk0;
#pragma unroll
      for (int j = 0; j < 16; j += 8) {
        *(v8s*)&whT[base + j] = *(v8s*)&hv[j];
        *(v8s*)&wlT[base + j] = *(v8s*)&lv[j];
      }
    }
    return;
  }
  bid -= 384;
  {  // ---- W0 [2048][256] -> w0T [256][2048], k-permuted ----
    const int e0 = (bid & 3) * 64;
    const int k0 = (bid >> 2) * 64;
    {
      const int row = tid >> 2;
      const int c0 = (tid & 3) * 16;
#pragma unroll
      for (int j = 0; j < 16; j += 4) {
        const float4 v = *(const float4*)&W0[(size_t)(k0 + row) * 256 + e0 + c0 + j];
        T[row][c0 + j + 0] = v.x; T[row][c0 + j + 1] = v.y;
        T[row][c0 + j + 2] = v.z; T[row][c0 + j + 3] = v.w;
      }
    }
    __syncthreads();
    {
      const int ee = tid >> 2;
      const int kk0 = (tid & 3) * 16;
#pragma unroll
      for (int j = 0; j < 16; ++j) {
        const int k = k0 + kk0 + j;      // original row = d*8+h
        const int d = k >> 3, h = k & 7;
        w0T[(size_t)(e0 + ee) * 2048 + h * 256 + d] = f2bf(T[kk0 + j][ee]);
      }
    }
  }
}

// ---------------------------------------------------------------------------
// Kernel A: qkv = x @ Wqkv + bqkv via MFMA.  q,k column-blocks: bf16x2
// (wh+wl); v blocks (c0>=4096): wh only.  grid (48, 32), 256 thr, 128x128.
// ---------------------------------------------------------------------------
__global__ __launch_bounds__(256) void qkv_mfma(
    const ushort* __restrict__ xb, const ushort* __restrict__ whT,
    const ushort* __restrict__ wlT, const float* __restrict__ bias,
    ushort* __restrict__ qkvb) {
  __shared__ ushort As[128 * 32];
  __shared__ ushort Bh[128 * 32];
  __shared__ ushort Bl[128 * 32];
  const int tid = threadIdx.x;
  const int wave = tid >> 6, lane = tid & 63;
  const int quad = lane >> 4, l15 = lane & 15;
  const int c0 = blockIdx.x * 128;
  const int r0 = blockIdx.y * 128;
  const bool isV = (c0 >= 4096);     // block-uniform: v needs no wl pass
  const int wr = (wave >> 1) * 64;
  const int wc = (wave & 1) * 64;

  v4f acc[4][4] = {};

  for (int d0 = 0; d0 < 256; d0 += 32) {
#pragma unroll
    for (int half = 0; half < 2; ++half) {
      const int rr = wave * 32 + half * 16;
      const int row = rr + (lane >> 2);
      const int gcol = d0 + (lane & 3) * 8;
      GLOAD_LDS16(xb + (size_t)(r0 + row) * 256 + gcol, &As[rr * 32]);
      GLOAD_LDS16(whT + (size_t)(c0 + row) * 256 + gcol, &Bh[rr * 32]);
      if (!isV) GLOAD_LDS16(wlT + (size_t)(c0 + row) * 256 + gcol, &Bl[rr * 32]);
    }
    __syncthreads();

    v8s aF[4], bh_[4], bl_[4];
#pragma unroll
    for (int i = 0; i < 4; ++i) {
      aF[i]  = *(const v8s*)&As[(wr + i * 16 + l15) * 32 + quad * 8];
      bh_[i] = *(const v8s*)&Bh[(wc + i * 16 + l15) * 32 + quad * 8];
    }
    if (!isV) {
#pragma unroll
      for (int i = 0; i < 4; ++i)
        bl_[i] = *(const v8s*)&Bl[(wc + i * 16 + l15) * 32 + quad * 8];
    }
#pragma unroll
    for (int ri = 0; ri < 4; ++ri)
#pragma unroll
      for (int ci = 0; ci < 4; ++ci)
        acc[ri][ci] = __builtin_amdgcn_mfma_f32_16x16x32_bf16(
            aF[ri], bh_[ci], acc[ri][ci], 0, 0, 0);
    if (!isV) {
#pragma unroll
      for (int ri = 0; ri < 4; ++ri)
#pragma unroll
        for (int ci = 0; ci < 4; ++ci)
          acc[ri][ci] = __builtin_amdgcn_mfma_f32_16x16x32_bf16(
              aF[ri], bl_[ci], acc[ri][ci], 0, 0, 0);
    }
    __syncthreads();
  }

  // Epilogue: C layout col=l15, row=quad*4+reg.  c' = seg*2048 + h*256 + d.
#pragma unroll
  for (int ci = 0; ci < 4; ++ci) {
    const int c = c0 + wc + ci * 16 + l15;
    const int cseg = c >> 11;
    const int h = (c & 2047) >> 8;
    const int d = c & 255;
    const float bv = bias[cseg * 2048 + d * 8 + h];
#pragma unroll
    for (int ri = 0; ri < 4; ++ri)
#pragma unroll
      for (int rg = 0; rg < 4; ++rg) {
        const int r = r0 + wr + ri * 16 + quad * 4 + rg;
        const int g = r * 3 + cseg;
        const int seg = g >> 12;       // q/k/v
        const int tok = g & 4095;      // = b*1024 + n
        float val = acc[ri][ci][rg] + bv;
        if (seg == 0) val *= 0.0625f;  // pre-scale q by D^-0.5
        qkvb[(size_t)seg * SEGSZ + (size_t)tok * 2048 + h * 256 + d] = f2bf(val);
      }
  }
}

// ---------------------------------------------------------------------------
// Kernel B: bf16 MFMA score stats over [tok][h*256+d] layout (stride 2048).
// grid (8 = t-tile, 8 = n-tile, 32 = b*h), 256 threads.
// ---------------------------------------------------------------------------
__global__ __launch_bounds__(256) void scores_mfma(
    const ushort* __restrict__ qkvb, float* __restrict__ pm,
    float* __restrict__ pl, float* __restrict__ sd_ws) {
  __shared__ ushort Qs[128 * 32];
  __shared__ ushort Ks[128 * 32];
  __shared__ float redM[2][2][64];
  __shared__ float redL[2][2][64];

  const int tid = threadIdx.x;
  const int wave = tid >> 6, lane = tid & 63;
  const int quad = lane >> 4, l15 = lane & 15;
  const int tt0 = blockIdx.x * 128;
  const int nn0 = blockIdx.y * 128;
  const int bh = blockIdx.z;
  const int b = bh >> 3, h = bh & 7;
  const ushort* Qg = qkvb + (size_t)b * 1024 * 2048 + h * 256;
  const ushort* Kg = Qg + SEGSZ;

  const int wr = (wave >> 1) * 64;
  const int wc = (wave & 1) * 64;

  v4f acc[4][4] = {};

  for (int d0 = 0; d0 < 256; d0 += 32) {
#pragma unroll
    for (int half = 0; half < 2; ++half) {
      const int rr = wave * 32 + half * 16;
      const int row = rr + (lane >> 2);
      const int gcol = d0 + (lane & 3) * 8;
      GLOAD_LDS16(Qg + (size_t)(nn0 + row) * 2048 + gcol, &Qs[rr * 32]);
      GLOAD_LDS16(Kg + (size_t)(tt0 + row) * 2048 + gcol, &Ks[rr * 32]);
    }
    __syncthreads();

    v8s aF[4], bF[4];
#pragma unroll
    for (int i = 0; i < 4; ++i) {
      aF[i] = *(const v8s*)&Qs[(wr + i * 16 + l15) * 32 + quad * 8];
      bF[i] = *(const v8s*)&Ks[(wc + i * 16 + l15) * 32 + quad * 8];
    }
#pragma unroll
    for (int ri = 0; ri < 4; ++ri)
#pragma unroll
      for (int ci = 0; ci < 4; ++ci)
        acc[ri][ci] =
            __builtin_amdgcn_mfma_f32_16x16x32_bf16(aF[ri], bF[ci], acc[ri][ci], 0, 0, 0);
    __syncthreads();
  }

  float mloc[4];
#pragma unroll
  for (int ci = 0; ci < 4; ++ci) {
    float m = acc[0][ci][0];
#pragma unroll
    for (int ri = 0; ri < 4; ++ri)
#pragma unroll
      for (int rg = 0; rg < 4; ++rg) m = fmaxf(m, acc[ri][ci][rg]);
    m = fmaxf(m, __shfl_xor(m, 16, 64));
    m = fmaxf(m, __shfl_xor(m, 32, 64));
    mloc[ci] = m;
  }
  if (quad == 0) {
#pragma unroll
    for (int ci = 0; ci < 4; ++ci)
      redM[wave & 1][wave >> 1][ci * 16 + l15] = mloc[ci];
  }
  __syncthreads();
  float mfull[4], lsum[4];
#pragma unroll
  for (int ci = 0; ci < 4; ++ci) {
    const float m = fmaxf(mloc[ci], redM[wave & 1][1 - (wave >> 1)][ci * 16 + l15]);
    mfull[ci] = m;
    float s = 0.f;
#pragma unroll
    for (int ri = 0; ri < 4; ++ri)
#pragma unroll
      for (int rg = 0; rg < 4; ++rg) s += __expf(acc[ri][ci][rg] - m);
    s += __shfl_xor(s, 16, 64);
    s += __shfl_xor(s, 32, 64);
    lsum[ci] = s;
  }
  if (quad == 0) {
#pragma unroll
    for (int ci = 0; ci < 4; ++ci)
      redL[wave & 1][wave >> 1][ci * 16 + l15] = lsum[ci];
  }
  __syncthreads();
  if ((wave >> 1) == 0 && quad == 0) {
#pragma unroll
    for (int ci = 0; ci < 4; ++ci) {
      const int t = tt0 + (wave & 1) * 64 + ci * 16 + l15;
      const float l = lsum[ci] + redL[wave & 1][1][ci * 16 + l15];
      const size_t idx = ((size_t)bh * 1024 + t) * 8 + blockIdx.y;
      pm[idx] = mfull[ci];
      pl[idx] = l;
    }
  }

  if (tt0 == nn0 && (wave == 0 || wave == 3) && quad == (l15 >> 2)) {
#pragma unroll
    for (int ri = 0; ri < 4; ++ri) {
      const int t = tt0 + (wave & 1) * 64 + ri * 16 + l15;
      sd_ws[(size_t)bh * 1024 + t] = acc[ri][ri][l15 & 3];
    }
  }
}

// ---------------------------------------------------------------------------
// Kernel C: out = (diag.v) @ W0 via bf16 MFMA, split-K BY HEAD.  diag is
// computed in-kernel from pm/pl/sd (merge fused).  bf16 partials.
// grid (2 = e-tile, 32 = tok-tile, 8 = h), 256 thr, 128x128 tile.
// ---------------------------------------------------------------------------
template <bool ATOMIC>
__global__ __launch_bounds__(256) void av_mfma(
    const ushort* __restrict__ vb, const ushort* __restrict__ w0T,
    const float* __restrict__ pm, const float* __restrict__ pl,
    const float* __restrict__ sd, ushort* __restrict__ partial,
    float* __restrict__ out) {
  __shared__ ushort As[128 * 32];
  __shared__ ushort Bs[128 * 32];
  __shared__ float diagS[128];
  const int tid = threadIdx.x;
  const int wave = tid >> 6, lane = tid & 63;
  const int quad = lane >> 4, l15 = lane & 15;
  const int e0 = blockIdx.x * 128;
  const int tok0 = blockIdx.y * 128;
  const int h = blockIdx.z;
  const int kbase = h * 256;
  const int wr = (wave >> 1) * 64;
  const int wc = (wave & 1) * 64;

  // fused merge_diag for this block's 128 tokens (covered by K-loop barrier)
  if (tid < 128) {
    const int bh = (tok0 >> 10) * 8 + h;
    const int t = (tok0 & 1023) + tid;
    const size_t base = ((size_t)bh * 1024 + t) * 8;
    float m = -1e30f;
#pragma unroll
    for (int c = 0; c < 8; ++c) m = fmaxf(m, pm[base + c]);
    float l = 0.f;
#pragma unroll
    for (int c = 0; c < 8; ++c) l += pl[base + c] * __expf(pm[base + c] - m);
    diagS[tid] = __expf(sd[(size_t)bh * 1024 + t] - m) / l;
  }

  v4f acc[4][4] = {};

  for (int d0 = 0; d0 < 256; d0 += 32) {
#pragma unroll
    for (int half = 0; half < 2; ++half) {
      const int rr = wave * 32 + half * 16;
      const int row = rr + (lane >> 2);
      const int gcol = kbase + d0 + (lane & 3) * 8;
      GLOAD_LDS16(vb + (size_t)(tok0 + row) * 2048 + gcol, &As[rr * 32]);
      GLOAD_LDS16(w0T + (size_t)(e0 + row) * 2048 + gcol, &Bs[rr * 32]);
    }
    __syncthreads();

    v8s aF[4], bF[4];
#pragma unroll
    for (int i = 0; i < 4; ++i) {
      aF[i] = *(const v8s*)&As[(wr + i * 16 + l15) * 32 + quad * 8];
      bF[i] = *(const v8s*)&Bs[(wc + i * 16 + l15) * 32 + quad * 8];
    }
#pragma unroll
    for (int ri = 0; ri < 4; ++ri)
#pragma unroll
      for (int ci = 0; ci < 4; ++ci)
        acc[ri][ci] =
            __builtin_amdgcn_mfma_f32_16x16x32_bf16(aF[ri], bF[ci], acc[ri][ci], 0, 0, 0);
    __syncthreads();
  }

#pragma unroll
  for (int ri = 0; ri < 4; ++ri)
#pragma unroll
    for (int rg = 0; rg < 4; ++rg) {
      const int lrow = wr + ri * 16 + quad * 4 + rg;
      const int tok = tok0 + lrow;
      const float dg = diagS[lrow];
#pragma unroll
      for (int ci = 0; ci < 4; ++ci) {
        const int e = e0 + wc + ci * 16 + l15;
        const float val = acc[ri][ci][rg] * dg;
        if (ATOMIC)
          atomicAdd(&out[(size_t)tok * 256 + e], val);
        else
          partial[(size_t)h * 1048576 + (size_t)tok * 256 + e] = f2bf(val);
      }
    }
}

__global__ void init_out(const float* __restrict__ b0, float* __restrict__ out) {
  const int i = blockIdx.x * 256 + threadIdx.x;
  const int e0 = (i & 63) << 2;
  *(float4*)&out[(size_t)i * 4] = *(const float4*)&b0[e0];
}

__global__ void reduce_out(const ushort* __restrict__ partial,
                           const float* __restrict__ b0, float* __restrict__ out) {
  const int i = blockIdx.x * 256 + threadIdx.x;  // 262144 float4 groups
  const int e0 = (i & 63) << 2;
  float4 a = *(const float4*)&b0[e0];
#pragma unroll
  for (int h = 0; h < 8; ++h) {
    const ushort4 p = *(const ushort4*)&partial[(size_t)h * 1048576 + (size_t)i * 4];
    a.x += bf2f(p.x); a.y += bf2f(p.y); a.z += bf2f(p.z); a.w += bf2f(p.w);
  }
  *(float4*)&out[(size_t)i * 4] = a;
}

extern "C" void kernel_launch(void* const* d_in, const int* in_sizes, int n_in,
                              void* d_out, int out_size, void* d_ws, size_t ws_size,
                              hipStream_t stream) {
  const float* x    = (const float*)d_in[0];
  const float* Wqkv = (const float*)d_in[1];
  const float* bqkv = (const float*)d_in[2];
  const float* W0   = (const float*)d_in[3];
  const float* b0   = (const float*)d_in[4];
  float* out = (float*)d_out;

  float*  pm   = (float*)d_ws;                     // 262144 f
  float*  pl   = pm + 262144;                      // 262144 f
  float*  sd   = pl + 262144;                      // 32768 f
  ushort* qkvb = (ushort*)(sd + 32768);            // 3*SEGSZ us (q|k|v)
  ushort* xb   = qkvb + 3 * (size_t)SEGSZ;         // 1048576 us
  ushort* whT  = xb + 1048576;                     // 1572864 us
  ushort* wlT  = whT + 1572864;                    // 1572864 us
  ushort* w0T  = wlT + 1572864;                    // 524288 us
  ushort* partial = w0T + 524288;                  // 8*1048576 us (optional)

  ushort* vb = qkvb + 2 * (size_t)SEGSZ;

  const size_t need_base =
      (size_t)(262144 * 2 + 32768) * 4 + (size_t)SEGSZ * 3 * 2 +
      (size_t)(1048576 + 1572864 * 2 + 524288) * 2;
  const bool full = ws_size >= need_base + (size_t)8 * 1048576 * 2;

  prep<<<1536, 256, 0, stream>>>(x, Wqkv, W0, xb, whT, wlT, w0T);
  qkv_mfma<<<dim3(48, 32), 256, 0, stream>>>(xb, whT, wlT, bqkv, qkvb);
  scores_mfma<<<dim3(8, 8, 32), 256, 0, stream>>>(qkvb, pm, pl, sd);
  if (full) {
    av_mfma<false><<<dim3(2, 32, 8), 256, 0, stream>>>(vb, w0T, pm, pl, sd, partial, out);
    reduce_out<<<1024, 256, 0, stream>>>(partial, b0, out);
  } else {
    init_out<<<1024, 256, 0, stream>>>(b0, out);
    av_mfma<true><<<dim3(2, 32, 8), 256, 0, stream>>>(vb, w0T, pm, pl, sd, nullptr, out);
  }
}